// Round 8
// baseline (124.079 us; speedup 1.0000x reference)
//
#include <hip/hip_runtime.h>
#include <hip/hip_bf16.h>
#include <math.h>

// ---------------- problem constants ----------------
#define T_TOK 4096
#define D_DIM 1024
#define I_DIM 512
#define E_EXP 8
#define KSEL 2
#define NPAIR (T_TOK * KSEL)          // 8192
#define ROUTED_CAP 10240              // >= 8192 + 7*255, multiple of 256 (40 tiles)
#define SHARED_BASE ROUTED_CAP        // 10240
#define RTOT (ROUTED_CAP + T_TOK)     // 14336
#define MAXTILES 56                   // <= 39 routed + 16 shared + slack
#define GRID_G (MAXTILES * 4)         // 224 = 8 XCDs x 28
#define NTRB 13824                    // transpose blocks in prep kernel

typedef __bf16 bf16x8 __attribute__((ext_vector_type(8)));
typedef float f32x4 __attribute__((ext_vector_type(4)));
typedef unsigned short ushort8 __attribute__((ext_vector_type(8)));

// ---------------- scratch layout (bytes) ----------------
constexpr size_t SZ_XB  = (size_t)T_TOK * D_DIM * 2;                 // 8.4 MB
constexpr size_t SZ_UG  = (size_t)E_EXP * 2 * I_DIM * D_DIM * 2;     // 16.8 MB
constexpr size_t SZ_DT  = (size_t)E_EXP * I_DIM * D_DIM * 2;         // 8.4 MB
constexpr size_t SZ_SUG = (size_t)2 * I_DIM * D_DIM * 2;             // 2.1 MB
constexpr size_t SZ_SDT = (size_t)I_DIM * D_DIM * 2;                 // 1.05 MB
constexpr size_t SZ_H   = (size_t)RTOT * I_DIM * 2;                  // 14.7 MB
constexpr size_t SZ_Y   = (size_t)RTOT * D_DIM * 2;                  // 29.4 MB

constexpr size_t OFF_XB   = 0;
constexpr size_t OFF_UG   = OFF_XB  + SZ_XB;
constexpr size_t OFF_DT   = OFF_UG  + SZ_UG;
constexpr size_t OFF_SUG  = OFF_DT  + SZ_DT;
constexpr size_t OFF_SDT  = OFF_SUG + SZ_SUG;
constexpr size_t OFF_H    = OFF_SDT + SZ_SDT;
constexpr size_t OFF_Y    = OFF_H   + SZ_H;
constexpr size_t OFF_TOPKI= OFF_Y   + SZ_Y;                 // NPAIR int
constexpr size_t OFF_TOPKW= OFF_TOPKI + (size_t)NPAIR * 4;  // NPAIR float
constexpr size_t OFF_INV  = OFF_TOPKW + (size_t)NPAIR * 4;  // NPAIR int
constexpr size_t OFF_PERM = OFF_INV   + (size_t)NPAIR * 4;  // RTOT int
constexpr size_t OFF_META = OFF_PERM  + (size_t)RTOT * 4;   // MAXTILES int2

// ---------------- helpers ----------------
__device__ __forceinline__ unsigned short f2bf(float f) {
  unsigned int u = __float_as_uint(f);
  unsigned int r = (u + 0x7FFFu + ((u >> 16) & 1u)) >> 16;
  return (unsigned short)r;
}
__device__ __forceinline__ float bf2f(unsigned short s) {
  return __uint_as_float(((unsigned int)s) << 16);
}
__device__ __forceinline__ void gload_lds16(const void* g, void* l) {
  __builtin_amdgcn_global_load_lds(
      (const __attribute__((address_space(1))) void*)g,
      (__attribute__((address_space(3))) void*)l, 16, 0, 0);
}

// ------- 1) prep: merged weight transpose-convert + gating (+x->bf16) -------
// bid < NTRB: transpose tiles (flat 256 threads emulating (32,8))
// bid >= NTRB: gating blocks (4 tokens each)
__global__ __launch_bounds__(256) void prep_kernel(
    const float* __restrict__ x,   const float* __restrict__ gw,
    const float* __restrict__ upw, const float* __restrict__ gpw,
    const float* __restrict__ dww, const float* __restrict__ sup,
    const float* __restrict__ sgt, const float* __restrict__ sdw,
    unsigned short* __restrict__ UG, unsigned short* __restrict__ sUG,
    unsigned short* __restrict__ Dt, unsigned short* __restrict__ sDt,
    unsigned short* __restrict__ xb,
    int* __restrict__ topk_idx, float* __restrict__ topk_w) {
  __shared__ float tbuf[32][33];
  int bid = blockIdx.x;
  int tid = threadIdx.x;
  if (bid < NTRB) {
    const float* in; unsigned short* out;
    int R, C, xt, yt, mode;
    if (bid < 4096)       { int e = bid >> 9, s = bid & 511;
      in = upw + (size_t)e * D_DIM * I_DIM; out = UG + (size_t)e * 2 * I_DIM * D_DIM;
      R = D_DIM; C = I_DIM; xt = s & 15; yt = s >> 4; mode = 0; }
    else if (bid < 8192)  { int b = bid - 4096; int e = b >> 9, s = b & 511;
      in = gpw + (size_t)e * D_DIM * I_DIM; out = UG + (size_t)e * 2 * I_DIM * D_DIM;
      R = D_DIM; C = I_DIM; xt = s & 15; yt = s >> 4; mode = 1; }
    else if (bid < 12288) { int b = bid - 8192; int e = b >> 9, s = b & 511;
      in = dww + (size_t)e * I_DIM * D_DIM; out = Dt + (size_t)e * I_DIM * D_DIM;
      R = I_DIM; C = D_DIM; xt = s & 31; yt = s >> 5; mode = 2; }
    else if (bid < 12800) { int s = bid - 12288;
      in = sup; out = sUG; R = D_DIM; C = I_DIM; xt = s & 15; yt = s >> 4; mode = 0; }
    else if (bid < 13312) { int s = bid - 12800;
      in = sgt; out = sUG; R = D_DIM; C = I_DIM; xt = s & 15; yt = s >> 4; mode = 1; }
    else                  { int s = bid - 13312;
      in = sdw; out = sDt; R = I_DIM; C = D_DIM; xt = s & 31; yt = s >> 5; mode = 2; }
    int c0 = xt * 32, r0 = yt * 32;
    int tx = tid & 31, ty = tid >> 5;              // emulate (32,8)
#pragma unroll
    for (int i = 0; i < 4; ++i)
      tbuf[ty + 8 * i][tx] = in[(size_t)(r0 + ty + 8 * i) * C + c0 + tx];
    __syncthreads();
#pragma unroll
    for (int i = 0; i < 4; ++i) {
      int c = c0 + ty + 8 * i;
      int orow = (mode == 2) ? c : (((c >> 4) << 5) + (c & 15) + (mode == 1 ? 16 : 0));
      out[(size_t)orow * R + r0 + tx] = f2bf(tbuf[tx][ty + 8 * i]);
    }
  } else {
    int lane = tid & 63;
    int t = (bid - NTRB) * 4 + (tid >> 6);         // wave per token
    const float4* xr = (const float4*)(x + (size_t)t * D_DIM);
    float4 xv[4];
#pragma unroll
    for (int j = 0; j < 4; ++j) xv[j] = xr[lane + 64 * j];
#pragma unroll
    for (int j = 0; j < 4; ++j) {
      ushort4 o;
      o.x = f2bf(xv[j].x); o.y = f2bf(xv[j].y); o.z = f2bf(xv[j].z); o.w = f2bf(xv[j].w);
      *(ushort4*)&xb[(size_t)t * D_DIM + (lane + 64 * j) * 4] = o;
    }
    float acc[E_EXP];
#pragma unroll
    for (int e = 0; e < E_EXP; ++e) {
      const float4* gr = (const float4*)(gw + (size_t)e * D_DIM);
      float a = 0.f;
#pragma unroll
      for (int j = 0; j < 4; ++j) {
        float4 g = gr[lane + 64 * j];
        a += xv[j].x * g.x + xv[j].y * g.y + xv[j].z * g.z + xv[j].w * g.w;
      }
      acc[e] = a;
    }
#pragma unroll
    for (int off = 32; off; off >>= 1)
#pragma unroll
      for (int e = 0; e < E_EXP; ++e) acc[e] += __shfl_xor(acc[e], off, 64);
    if (lane == 0) {
      int i0 = 0; float m0 = acc[0];
#pragma unroll
      for (int e = 1; e < E_EXP; ++e) if (acc[e] > m0) { m0 = acc[e]; i0 = e; }
      int i1 = -1; float m1 = -1e30f;
#pragma unroll
      for (int e = 0; e < E_EXP; ++e) if (e != i0 && acc[e] > m1) { m1 = acc[e]; i1 = e; }
      float e1 = __expf(m1 - m0);
      float w0 = 1.0f / (1.0f + e1);
      float w1 = e1 / (1.0f + e1);
      topk_idx[2 * t] = i0; topk_idx[2 * t + 1] = i1;
      topk_w[2 * t] = w0;   topk_w[2 * t + 1] = w1;
    }
  }
}

// ---------------- 2) route: counts+offsets+meta+perm+inv, zero atomics --------
__global__ __launch_bounds__(1024) void route_kernel(
    const int* __restrict__ tidx, int* __restrict__ meta,
    int* __restrict__ perm, int* __restrict__ inv) {
  __shared__ int els[NPAIR];            // 32 KB
  __shared__ int cnt_iw[128][E_EXP];
  __shared__ int base_iw[128][E_EXP];
  __shared__ int ebase[E_EXP];
  __shared__ int ecnt[E_EXP];
  int tid = threadIdx.x, lane = tid & 63, wv = tid >> 6;   // 16 waves

  for (int it = 0; it < NPAIR / 1024; ++it) {              // 8 iters
    int g = it * 1024 + tid;
    int e = tidx[g];
    els[g] = e;
#pragma unroll
    for (int ex = 0; ex < E_EXP; ++ex) {
      unsigned long long m = __ballot(e == ex);
      if (lane == 0) cnt_iw[it * 16 + wv][ex] = __popcll(m);
    }
  }
  __syncthreads();

  if (tid < E_EXP) {
    int s = 0;
    for (int iw = 0; iw < 128; ++iw) { base_iw[iw][tid] = s; s += cnt_iw[iw][tid]; }
    ecnt[tid] = s;
  }
  __syncthreads();

  if (tid == 0) {
    int o = 0, tc = 0;
    int2* m2 = (int2*)meta;
    for (int e = 0; e < E_EXP; ++e) {
      ebase[e] = o;
      int c = ecnt[e];
      int pt = (c + 255) >> 8;
      for (int ti = 0; ti < pt; ++ti) m2[tc++] = make_int2(e, o + ti * 256);
      o += pt * 256;
    }
    for (int ti = 0; ti < T_TOK / 256; ++ti)
      m2[tc++] = make_int2(E_EXP, SHARED_BASE + ti * 256);
    for (; tc < MAXTILES; ++tc) m2[tc] = make_int2(-1, 0);
  }
  __syncthreads();

  for (int it = 0; it < NPAIR / 1024; ++it) {
    int g = it * 1024 + tid;
    int e = els[g];
    int rank = 0;
#pragma unroll
    for (int ex = 0; ex < E_EXP; ++ex) {
      unsigned long long m = __ballot(e == ex);
      if (e == ex) rank = __popcll(m & ((1ull << lane) - 1ull));
    }
    int row = ebase[e] + base_iw[it * 16 + wv][e] + rank;
    perm[row] = g >> 1;
    inv[g] = row;
  }
  for (int p = tid; p < E_EXP * 256; p += 1024) {          // pad rows -> token 0
    int e = p >> 8, s = p & 255;
    int c = ecnt[e];
    int padn = (((c + 255) >> 8) << 8) - c;
    if (s < padn) perm[ebase[e] + c + s] = 0;
  }
  for (int t = tid; t < T_TOK; t += 1024) perm[SHARED_BASE + t] = t;
}

// -------- 3) GEMM1: 256x256, fine 8-phase (5 barriers/K-tile), counted vmcnt --
// EXPERIMENT ARM: m201-style per-phase barrier pairs; gemm2 is the 2-phase control.
__global__ __launch_bounds__(512, 2) void gemm1_kernel(
    const unsigned short* __restrict__ xb, const unsigned short* __restrict__ UG,
    const unsigned short* __restrict__ sUG, unsigned short* __restrict__ H,
    const int* __restrict__ meta, const int* __restrict__ perm) {
  int orig = blockIdx.x;
  int wg = (orig & 7) * (GRID_G / 8) + (orig >> 3);  // XCD chunk swizzle (bijective)
  int mt = wg >> 2, nt = wg & 3;
  int2 m2 = ((const int2*)meta)[mt];
  int e = m2.x;
  if (e < 0) return;
  int base = m2.y;
  int n0 = nt * 256;
  const unsigned short* B = (e < E_EXP) ? UG + (size_t)e * 2 * I_DIM * D_DIM : sUG;

  __shared__ unsigned short As[2 * 256 * 64];   // 64 KB (dbuf)
  __shared__ unsigned short Bs[2 * 256 * 64];   // 64 KB

  int tid = threadIdx.x, lane = tid & 63, wv = tid >> 6;   // 8 waves
  const unsigned short *gA[4], *gB[4];
  int dL[4];
#pragma unroll
  for (int j = 0; j < 4; ++j) {
    int c = j * 512 + tid;
    int row = c >> 3, q = c & 7, qs = q ^ (row & 7);
    int tok = perm[base + row];
    gA[j] = xb + (size_t)tok * D_DIM + qs * 8;
    gB[j] = B + (size_t)(n0 + row) * D_DIM + qs * 8;
    dL[j] = (j * 512 + wv * 64) * 8;             // wave-uniform 16B-linear dest
  }

  f32x4 acc[8][4] = {};
  int wr = (wv >> 2) * 128, wc = (wv & 3) * 64;  // 2x4 wave grid, 128x64 each
  int l15 = lane & 15, l4 = lane >> 4;
  int sx = l15 & 7;                              // read-side XOR term

#define LOAD2_1(j, buf, k0) do { \
    gload_lds16(gA[j] + (k0), As + (buf) * 16384 + dL[j]); \
    gload_lds16(gB[j] + (k0), Bs + (buf) * 16384 + dL[j]); } while (0)

#define MFMA16(lo) do { \
    __builtin_amdgcn_s_setprio(1); \
    _Pragma("unroll") \
    for (int i = 0; i < 4; ++i) \
      _Pragma("unroll") \
      for (int j = 0; j < 4; ++j) \
        acc[(lo) + i][j] = __builtin_amdgcn_mfma_f32_16x16x32_bf16(af[i], bfr[j], acc[(lo) + i][j], 0, 0, 0); \
    __builtin_amdgcn_s_setprio(0); } while (0)

  // prologue: stage tile 0 fully into buf 0
#pragma unroll
  for (int j = 0; j < 4; ++j) LOAD2_1(j, 0, 0);

  const int NK = D_DIM / 64;                     // 16
  for (int t = 0; t < NK; ++t) {
    int cur = t & 1, nxt = cur ^ 1;
    int kn = (t + 1) * 64;
    bool pf = (t + 1 < NK);
    const unsigned short* Ac = As + cur * 16384;
    const unsigned short* Bc = Bs + cur * 16384;
    bf16x8 af[4], bfr[4];
    int kb0 = l4 ^ sx, kb1 = (4 + l4) ^ sx;

    // ---- phase 0: stage g0 | vmcnt | barrier | ds(bfr kh0 + af r0-3) | MFMA ----
    if (pf) { LOAD2_1(0, nxt, kn);
      asm volatile("s_waitcnt vmcnt(2)" ::: "memory");   // tile t's 8 loads done
    } else {
      asm volatile("s_waitcnt vmcnt(0)" ::: "memory");
    }
    __builtin_amdgcn_s_barrier();                // all waves' tile-t loads visible
#pragma unroll
    for (int j = 0; j < 4; ++j) bfr[j] = *(const bf16x8*)&Bc[(wc + j * 16 + l15) * 64 + kb0 * 8];
#pragma unroll
    for (int i = 0; i < 4; ++i) af[i] = *(const bf16x8*)&Ac[(wr + i * 16 + l15) * 64 + kb0 * 8];
    asm volatile("s_waitcnt lgkmcnt(0)" ::: "memory");
    __builtin_amdgcn_sched_barrier(0);           // rule 18: stop MFMA hoist
    MFMA16(0);
    __builtin_amdgcn_s_barrier();
    // ---- phase 1: stage g1 | ds(af r4-7) | MFMA (bfr reused) ----
    if (pf) LOAD2_1(1, nxt, kn);
#pragma unroll
    for (int i = 0; i < 4; ++i) af[i] = *(const bf16x8*)&Ac[(wr + (4 + i) * 16 + l15) * 64 + kb0 * 8];
    asm volatile("s_waitcnt lgkmcnt(0)" ::: "memory");
    __builtin_amdgcn_sched_barrier(0);
    MFMA16(4);
    __builtin_amdgcn_s_barrier();
    // ---- phase 2: stage g2 | ds(bfr kh1 + af r0-3) | MFMA ----
    if (pf) LOAD2_1(2, nxt, kn);
#pragma unroll
    for (int j = 0; j < 4; ++j) bfr[j] = *(const bf16x8*)&Bc[(wc + j * 16 + l15) * 64 + kb1 * 8];
#pragma unroll
    for (int i = 0; i < 4; ++i) af[i] = *(const bf16x8*)&Ac[(wr + i * 16 + l15) * 64 + kb1 * 8];
    asm volatile("s_waitcnt lgkmcnt(0)" ::: "memory");
    __builtin_amdgcn_sched_barrier(0);
    MFMA16(0);
    __builtin_amdgcn_s_barrier();
    // ---- phase 3: stage g3 | ds(af r4-7) | MFMA ----
    if (pf) LOAD2_1(3, nxt, kn);
#pragma unroll
    for (int i = 0; i < 4; ++i) af[i] = *(const bf16x8*)&Ac[(wr + (4 + i) * 16 + l15) * 64 + kb1 * 8];
    asm volatile("s_waitcnt lgkmcnt(0)" ::: "memory");
    __builtin_amdgcn_sched_barrier(0);
    MFMA16(4);
    __builtin_amdgcn_s_barrier();                // protects buf nxt WAR at t+1 stage
  }
#undef LOAD2_1
#undef MFMA16

  // epilogue: frag pair (2p, 2p+1) = (U, G) for one 16-col H block
  const float is2 = 0.70710678118654752f;
  int cb = ((n0 + wc) >> 1);
#pragma unroll
  for (int i = 0; i < 8; ++i) {
    int row = base + wr + i * 16 + l4 * 4;
#pragma unroll
    for (int p = 0; p < 2; ++p) {
      int col = cb + p * 16 + l15;
#pragma unroll
      for (int r = 0; r < 4; ++r) {
        float u = acc[i][2 * p][r], g = acc[i][2 * p + 1][r];
        float gl = 0.5f * g * (1.0f + erff(g * is2));
        H[(size_t)(row + r) * I_DIM + col] = f2bf(u * gl);
      }
    }
  }
}

// -------- 4) GEMM2 (CONTROL, R6 2-phase): 256x256, dbuf, counted vmcnt --------
__global__ __launch_bounds__(512, 2) void gemm2_kernel(
    const unsigned short* __restrict__ H, const unsigned short* __restrict__ Dt,
    const unsigned short* __restrict__ sDt, unsigned short* __restrict__ Y,
    const int* __restrict__ meta) {
  int orig = blockIdx.x;
  int wg = (orig & 7) * (GRID_G / 8) + (orig >> 3);
  int mt = wg >> 2, nt = wg & 3;
  int2 m2 = ((const int2*)meta)[mt];
  int e = m2.x;
  if (e < 0) return;
  int base = m2.y;
  int n0 = nt * 256;
  const unsigned short* B = (e < E_EXP) ? Dt + (size_t)e * D_DIM * I_DIM : sDt;

  __shared__ unsigned short As[2 * 256 * 64];
  __shared__ unsigned short Bs[2 * 256 * 64];

  int tid = threadIdx.x, lane = tid & 63, wv = tid >> 6;
  const unsigned short *gA[4], *gB[4];
  int dL[4];
#pragma unroll
  for (int j = 0; j < 4; ++j) {
    int c = j * 512 + tid;
    int row = c >> 3, q = c & 7, qs = q ^ (row & 7);
    gA[j] = H + (size_t)(base + row) * I_DIM + qs * 8;
    gB[j] = B + (size_t)(n0 + row) * I_DIM + qs * 8;
    dL[j] = (j * 512 + wv * 64) * 8;
  }

  f32x4 acc[8][4] = {};
  int wr = (wv >> 2) * 128, wc = (wv & 3) * 64;
  int l15 = lane & 15, l4 = lane >> 4;
  int sx = l15 & 7;

#define STAGE2(buf, k0) do { \
  _Pragma("unroll") \
  for (int j = 0; j < 4; ++j) { \
    gload_lds16(gA[j] + (k0), As + (buf) * 16384 + dL[j]); \
    gload_lds16(gB[j] + (k0), Bs + (buf) * 16384 + dL[j]); \
  } } while (0)

  STAGE2(0, 0);
  const int NK = I_DIM / 64;                     // 8
  for (int t = 0; t < NK; ++t) {
    int cur = t & 1;
    if (t + 1 < NK) {
      STAGE2(cur ^ 1, (t + 1) * 64);
      asm volatile("s_waitcnt vmcnt(8)" ::: "memory");
    } else {
      asm volatile("s_waitcnt vmcnt(0)" ::: "memory");
    }
    __builtin_amdgcn_s_barrier();
#pragma unroll
    for (int kh = 0; kh < 2; ++kh) {
      int kb = kh * 4 + l4;
      bf16x8 af[8], bfr[4];
#pragma unroll
      for (int i = 0; i < 8; ++i)
        af[i] = *(const bf16x8*)&As[cur * 16384 + (wr + i * 16 + l15) * 64 + ((kb ^ sx)) * 8];
#pragma unroll
      for (int j = 0; j < 4; ++j)
        bfr[j] = *(const bf16x8*)&Bs[cur * 16384 + (wc + j * 16 + l15) * 64 + ((kb ^ sx)) * 8];
      __builtin_amdgcn_s_setprio(1);
#pragma unroll
      for (int i = 0; i < 8; ++i)
#pragma unroll
        for (int j = 0; j < 4; ++j)
          acc[i][j] = __builtin_amdgcn_mfma_f32_16x16x32_bf16(af[i], bfr[j], acc[i][j], 0, 0, 0);
      __builtin_amdgcn_s_setprio(0);
    }
    asm volatile("" ::: "memory");
    __builtin_amdgcn_s_barrier();
  }
#undef STAGE2

#pragma unroll
  for (int i = 0; i < 8; ++i) {
    int row = base + wr + i * 16 + l4 * 4;
#pragma unroll
    for (int j = 0; j < 4; ++j) {
      int col = n0 + wc + j * 16 + l15;
#pragma unroll
      for (int r = 0; r < 4; ++r)
        Y[(size_t)(row + r) * D_DIM + col] = f2bf(acc[i][j][r]);
    }
  }
}

// ---------------- 5) combine: out = w0*Y[r0] + w1*Y[r1] + Y[shared] ----------------
__global__ void combine_kernel(const unsigned short* __restrict__ Y, const int* __restrict__ inv,
                               const float* __restrict__ tw, float* __restrict__ out) {
  int g = blockIdx.x * 256 + threadIdx.x;
  int t = g >> 7, d0 = (g & 127) * 8;
  int r0 = inv[2 * t], r1 = inv[2 * t + 1];
  float w0 = tw[2 * t], w1 = tw[2 * t + 1];
  ushort8 y0 = *(const ushort8*)&Y[(size_t)r0 * D_DIM + d0];
  ushort8 y1 = *(const ushort8*)&Y[(size_t)r1 * D_DIM + d0];
  ushort8 ys = *(const ushort8*)&Y[(size_t)(SHARED_BASE + t) * D_DIM + d0];
  float o[8];
#pragma unroll
  for (int j = 0; j < 8; ++j)
    o[j] = w0 * bf2f(y0[j]) + w1 * bf2f(y1[j]) + bf2f(ys[j]);
  float4* op = (float4*)(out + (size_t)t * D_DIM + d0);
  op[0] = make_float4(o[0], o[1], o[2], o[3]);
  op[1] = make_float4(o[4], o[5], o[6], o[7]);
}

// ---------------- launcher ----------------
extern "C" void kernel_launch(void* const* d_in, const int* in_sizes, int n_in,
                              void* d_out, int out_size, void* d_ws, size_t ws_size,
                              hipStream_t stream) {
  const float* x    = (const float*)d_in[0];
  const float* gw   = (const float*)d_in[1];
  const float* upw  = (const float*)d_in[2];
  const float* gpw  = (const float*)d_in[3];
  const float* dww  = (const float*)d_in[4];
  const float* sup  = (const float*)d_in[5];
  const float* sgt  = (const float*)d_in[6];
  const float* sdw  = (const float*)d_in[7];
  float* out = (float*)d_out;

  char* ws = (char*)d_ws;
  unsigned short* xb  = (unsigned short*)(ws + OFF_XB);
  unsigned short* UG  = (unsigned short*)(ws + OFF_UG);
  unsigned short* Dt  = (unsigned short*)(ws + OFF_DT);
  unsigned short* sUG = (unsigned short*)(ws + OFF_SUG);
  unsigned short* sDt = (unsigned short*)(ws + OFF_SDT);
  unsigned short* H   = (unsigned short*)(ws + OFF_H);
  unsigned short* Y   = (unsigned short*)(ws + OFF_Y);
  int*   tki   = (int*)(ws + OFF_TOPKI);
  float* tkw   = (float*)(ws + OFF_TOPKW);
  int*   inv   = (int*)(ws + OFF_INV);
  int*   perm  = (int*)(ws + OFF_PERM);
  int*   meta  = (int*)(ws + OFF_META);

  prep_kernel<<<NTRB + T_TOK / 4, 256, 0, stream>>>(x, gw, upw, gpw, dww, sup, sgt, sdw,
                                                    UG, sUG, Dt, sDt, xb, tki, tkw);
  route_kernel<<<1, 1024, 0, stream>>>(tki, meta, perm, inv);

  gemm1_kernel<<<GRID_G, 512, 0, stream>>>(xb, UG, sUG, H, meta, perm);
  gemm2_kernel<<<GRID_G, 512, 0, stream>>>(H, Dt, sDt, Y, meta);
  combine_kernel<<<(T_TOK * 128) / 256, 256, 0, stream>>>(Y, inv, tkw, out);
}

// Round 9
// 118.734 us; speedup vs baseline: 1.0450x; 1.0450x over previous
//
#include <hip/hip_runtime.h>
#include <hip/hip_bf16.h>
#include <math.h>

// ---------------- problem constants ----------------
#define T_TOK 4096
#define D_DIM 1024
#define I_DIM 512
#define E_EXP 8
#define KSEL 2
#define NPAIR (T_TOK * KSEL)          // 8192
#define ROUTED_CAP 10240              // >= 8192 + 7*255, multiple of 256 (40 tiles)
#define SHARED_BASE ROUTED_CAP        // 10240
#define RTOT (ROUTED_CAP + T_TOK)     // 14336
#define MAXTILES 56                   // <= 39 routed + 16 shared + slack
#define GRID_G (MAXTILES * 4)         // 224 = 8 XCDs x 28

typedef __bf16 bf16x8 __attribute__((ext_vector_type(8)));
typedef float f32x4 __attribute__((ext_vector_type(4)));
typedef unsigned short ushort8 __attribute__((ext_vector_type(8)));

// ---------------- scratch layout (bytes) ----------------
constexpr size_t SZ_XB  = (size_t)T_TOK * D_DIM * 2;                 // 8.4 MB
constexpr size_t SZ_UG  = (size_t)E_EXP * 2 * I_DIM * D_DIM * 2;     // 16.8 MB
constexpr size_t SZ_DT  = (size_t)E_EXP * I_DIM * D_DIM * 2;         // 8.4 MB
constexpr size_t SZ_SUG = (size_t)2 * I_DIM * D_DIM * 2;             // 2.1 MB
constexpr size_t SZ_SDT = (size_t)I_DIM * D_DIM * 2;                 // 1.05 MB
constexpr size_t SZ_H   = (size_t)RTOT * I_DIM * 2;                  // 14.7 MB
constexpr size_t SZ_Y   = (size_t)RTOT * D_DIM * 2;                  // 29.4 MB

constexpr size_t OFF_XB   = 0;
constexpr size_t OFF_UG   = OFF_XB  + SZ_XB;
constexpr size_t OFF_DT   = OFF_UG  + SZ_UG;
constexpr size_t OFF_SUG  = OFF_DT  + SZ_DT;
constexpr size_t OFF_SDT  = OFF_SUG + SZ_SUG;
constexpr size_t OFF_H    = OFF_SDT + SZ_SDT;
constexpr size_t OFF_Y    = OFF_H   + SZ_H;
constexpr size_t OFF_TOPKI= OFF_Y   + SZ_Y;                 // NPAIR int
constexpr size_t OFF_TOPKW= OFF_TOPKI + (size_t)NPAIR * 4;  // NPAIR float
constexpr size_t OFF_INV  = OFF_TOPKW + (size_t)NPAIR * 4;  // NPAIR int
constexpr size_t OFF_PERM = OFF_INV   + (size_t)NPAIR * 4;  // RTOT int
constexpr size_t OFF_META = OFF_PERM  + (size_t)RTOT * 4;   // MAXTILES int2

// ---------------- helpers ----------------
__device__ __forceinline__ unsigned short f2bf(float f) {
  unsigned int u = __float_as_uint(f);
  unsigned int r = (u + 0x7FFFu + ((u >> 16) & 1u)) >> 16;
  return (unsigned short)r;
}
__device__ __forceinline__ float bf2f(unsigned short s) {
  return __uint_as_float(((unsigned int)s) << 16);
}
__device__ __forceinline__ void gload_lds16(const void* g, void* l) {
  __builtin_amdgcn_global_load_lds(
      (const __attribute__((address_space(1))) void*)g,
      (__attribute__((address_space(3))) void*)l, 16, 0, 0);
}

// ---------------- 1) merged transpose-convert of ALL weights --------------
__global__ void transpose_cvt_all(
    const float* __restrict__ upw, const float* __restrict__ gpw,
    const float* __restrict__ dww, const float* __restrict__ sup,
    const float* __restrict__ sgt, const float* __restrict__ sdw,
    unsigned short* __restrict__ UG, unsigned short* __restrict__ sUG,
    unsigned short* __restrict__ Dt, unsigned short* __restrict__ sDt) {
  __shared__ float t[32][33];
  int bid = blockIdx.x;
  const float* in; unsigned short* out;
  int R, C, xt, yt, mode;
  if (bid < 4096)       { int e = bid >> 9, s = bid & 511;
    in = upw + (size_t)e * D_DIM * I_DIM; out = UG + (size_t)e * 2 * I_DIM * D_DIM;
    R = D_DIM; C = I_DIM; xt = s & 15; yt = s >> 4; mode = 0; }
  else if (bid < 8192)  { int b = bid - 4096; int e = b >> 9, s = b & 511;
    in = gpw + (size_t)e * D_DIM * I_DIM; out = UG + (size_t)e * 2 * I_DIM * D_DIM;
    R = D_DIM; C = I_DIM; xt = s & 15; yt = s >> 4; mode = 1; }
  else if (bid < 12288) { int b = bid - 8192; int e = b >> 9, s = b & 511;
    in = dww + (size_t)e * I_DIM * D_DIM; out = Dt + (size_t)e * I_DIM * D_DIM;
    R = I_DIM; C = D_DIM; xt = s & 31; yt = s >> 5; mode = 2; }
  else if (bid < 12800) { int s = bid - 12288;
    in = sup; out = sUG; R = D_DIM; C = I_DIM; xt = s & 15; yt = s >> 4; mode = 0; }
  else if (bid < 13312) { int s = bid - 12800;
    in = sgt; out = sUG; R = D_DIM; C = I_DIM; xt = s & 15; yt = s >> 4; mode = 1; }
  else                  { int s = bid - 13312;
    in = sdw; out = sDt; R = I_DIM; C = D_DIM; xt = s & 31; yt = s >> 5; mode = 2; }
  int c0 = xt * 32, r0 = yt * 32;
  int tx = threadIdx.x, ty = threadIdx.y;          // block (32,8)
#pragma unroll
  for (int i = 0; i < 4; ++i)
    t[ty + 8 * i][tx] = in[(size_t)(r0 + ty + 8 * i) * C + c0 + tx];
  __syncthreads();
#pragma unroll
  for (int i = 0; i < 4; ++i) {
    int c = c0 + ty + 8 * i;
    int orow = (mode == 2) ? c : (((c >> 4) << 5) + (c & 15) + (mode == 1 ? 16 : 0));
    out[(size_t)orow * R + r0 + tx] = f2bf(t[tx][ty + 8 * i]);
  }
}

// ---------------- 2) gating (+ fused x->bf16): logits, top-2, renorm ----------
__global__ void gating_kernel(const float* __restrict__ x, const float* __restrict__ gw,
                              unsigned short* __restrict__ xb,
                              int* __restrict__ topk_idx, float* __restrict__ topk_w) {
  int lane = threadIdx.x & 63;
  int t = blockIdx.x * 4 + (threadIdx.x >> 6);     // wave per token
  const float4* xr = (const float4*)(x + (size_t)t * D_DIM);
  float4 xv[4];
#pragma unroll
  for (int j = 0; j < 4; ++j) xv[j] = xr[lane + 64 * j];
#pragma unroll
  for (int j = 0; j < 4; ++j) {
    ushort4 o;
    o.x = f2bf(xv[j].x); o.y = f2bf(xv[j].y); o.z = f2bf(xv[j].z); o.w = f2bf(xv[j].w);
    *(ushort4*)&xb[(size_t)t * D_DIM + (lane + 64 * j) * 4] = o;
  }
  float acc[E_EXP];
#pragma unroll
  for (int e = 0; e < E_EXP; ++e) {
    const float4* gr = (const float4*)(gw + (size_t)e * D_DIM);
    float a = 0.f;
#pragma unroll
    for (int j = 0; j < 4; ++j) {
      float4 g = gr[lane + 64 * j];
      a += xv[j].x * g.x + xv[j].y * g.y + xv[j].z * g.z + xv[j].w * g.w;
    }
    acc[e] = a;
  }
#pragma unroll
  for (int off = 32; off; off >>= 1)
#pragma unroll
    for (int e = 0; e < E_EXP; ++e) acc[e] += __shfl_xor(acc[e], off, 64);
  if (lane == 0) {
    int i0 = 0; float m0 = acc[0];
#pragma unroll
    for (int e = 1; e < E_EXP; ++e) if (acc[e] > m0) { m0 = acc[e]; i0 = e; }
    int i1 = -1; float m1 = -1e30f;
#pragma unroll
    for (int e = 0; e < E_EXP; ++e) if (e != i0 && acc[e] > m1) { m1 = acc[e]; i1 = e; }
    float e1 = __expf(m1 - m0);
    float w0 = 1.0f / (1.0f + e1);
    float w1 = e1 / (1.0f + e1);
    topk_idx[2 * t] = i0; topk_idx[2 * t + 1] = i1;
    topk_w[2 * t] = w0;   topk_w[2 * t + 1] = w1;
  }
}

// ---------------- 3) route: counts+offsets+meta+perm+inv, zero atomics --------
__global__ __launch_bounds__(1024) void route_kernel(
    const int* __restrict__ tidx, int* __restrict__ meta,
    int* __restrict__ perm, int* __restrict__ inv) {
  __shared__ int els[NPAIR];            // 32 KB
  __shared__ int cnt_iw[128][E_EXP];
  __shared__ int base_iw[128][E_EXP];
  __shared__ int ebase[E_EXP];
  __shared__ int ecnt[E_EXP];
  int tid = threadIdx.x, lane = tid & 63, wv = tid >> 6;   // 16 waves

  for (int it = 0; it < NPAIR / 1024; ++it) {              // 8 iters
    int g = it * 1024 + tid;
    int e = tidx[g];
    els[g] = e;
#pragma unroll
    for (int ex = 0; ex < E_EXP; ++ex) {
      unsigned long long m = __ballot(e == ex);
      if (lane == 0) cnt_iw[it * 16 + wv][ex] = __popcll(m);
    }
  }
  __syncthreads();

  if (tid < E_EXP) {
    int s = 0;
    for (int iw = 0; iw < 128; ++iw) { base_iw[iw][tid] = s; s += cnt_iw[iw][tid]; }
    ecnt[tid] = s;
  }
  __syncthreads();

  if (tid == 0) {
    int o = 0, tc = 0;
    int2* m2 = (int2*)meta;
    for (int e = 0; e < E_EXP; ++e) {
      ebase[e] = o;
      int c = ecnt[e];
      int pt = (c + 255) >> 8;
      for (int ti = 0; ti < pt; ++ti) m2[tc++] = make_int2(e, o + ti * 256);
      o += pt * 256;
    }
    for (int ti = 0; ti < T_TOK / 256; ++ti)
      m2[tc++] = make_int2(E_EXP, SHARED_BASE + ti * 256);
    for (; tc < MAXTILES; ++tc) m2[tc] = make_int2(-1, 0);
  }
  __syncthreads();

  for (int it = 0; it < NPAIR / 1024; ++it) {
    int g = it * 1024 + tid;
    int e = els[g];
    int rank = 0;
#pragma unroll
    for (int ex = 0; ex < E_EXP; ++ex) {
      unsigned long long m = __ballot(e == ex);
      if (e == ex) rank = __popcll(m & ((1ull << lane) - 1ull));
    }
    int row = ebase[e] + base_iw[it * 16 + wv][e] + rank;
    perm[row] = g >> 1;
    inv[g] = row;
  }
  for (int p = tid; p < E_EXP * 256; p += 1024) {          // pad rows -> token 0
    int e = p >> 8, s = p & 255;
    int c = ecnt[e];
    int padn = (((c + 255) >> 8) << 8) - c;
    if (s < padn) perm[ebase[e] + c + s] = 0;
  }
  for (int t = tid; t < T_TOK; t += 1024) perm[SHARED_BASE + t] = t;
}

// -------- 4) GEMM1 (ARM): 256x256, BK=32, QUAD buffer, prefetch depth 3 -------
// One barrier + one counted vmcnt per K-tile; vmcnt waits on loads issued
// 3 K-tiles ago. Stage issued AFTER the barrier (WAR-safe: buf (t+3)&3 was
// last read at tile t-1, and the barrier proves all waves finished t-1).
__global__ __launch_bounds__(512, 2) void gemm1_kernel(
    const unsigned short* __restrict__ xb, const unsigned short* __restrict__ UG,
    const unsigned short* __restrict__ sUG, unsigned short* __restrict__ H,
    const int* __restrict__ meta, const int* __restrict__ perm) {
  int orig = blockIdx.x;
  int wg = (orig & 7) * (GRID_G / 8) + (orig >> 3);  // XCD chunk swizzle (bijective)
  int mt = wg >> 2, nt = wg & 3;
  int2 m2 = ((const int2*)meta)[mt];
  int e = m2.x;
  if (e < 0) return;
  int base = m2.y;
  int n0 = nt * 256;
  const unsigned short* B = (e < E_EXP) ? UG + (size_t)e * 2 * I_DIM * D_DIM : sUG;

  __shared__ unsigned short As[4 * 256 * 32];   // 64 KB (quad buffer, 16 KB each)
  __shared__ unsigned short Bs[4 * 256 * 32];   // 64 KB

  int tid = threadIdx.x, lane = tid & 63, wv = tid >> 6;   // 8 waves
  // per K-tile per matrix: 1024 16B chunks (256 rows x 4 quads), 2/thread.
  // chunk c: row=c>>2, q=c&3; source quad swizzled qs=q^(row&3); LDS linear.
  const unsigned short *gA[2], *gB[2];
  int dL[2];
#pragma unroll
  for (int j = 0; j < 2; ++j) {
    int c = j * 512 + tid;
    int row = c >> 2, q = c & 3, qs = q ^ (row & 3);
    int tok = perm[base + row];
    gA[j] = xb + (size_t)tok * D_DIM + qs * 8;
    gB[j] = B + (size_t)(n0 + row) * D_DIM + qs * 8;
    dL[j] = (j * 512 + wv * 64) * 8;             // wave-uniform 16B-linear dest
  }

  f32x4 acc[8][4] = {};
  int wr = (wv >> 2) * 128, wc = (wv & 3) * 64;  // 2x4 wave grid, 128x64 each
  int l15 = lane & 15, l4 = lane >> 4;
  int sx = l15 & 3;                              // read-side XOR (4 quads)

#define STG1(bufi, k0) do { \
  _Pragma("unroll") \
  for (int j = 0; j < 2; ++j) { \
    gload_lds16(gA[j] + (k0), As + (bufi) * 8192 + dL[j]); \
    gload_lds16(gB[j] + (k0), Bs + (bufi) * 8192 + dL[j]); \
  } } while (0)

  // prologue: stage tiles 0,1,2 (12 insts in flight max)
  STG1(0, 0); STG1(1, 32); STG1(2, 64);

  const int NK = D_DIM / 32;                     // 32
  for (int t = 0; t < NK; ++t) {
    int p = t & 3;
    if (t < NK - 2)      asm volatile("s_waitcnt vmcnt(8)" ::: "memory");  // tile t done (3 tiles old)
    else if (t < NK - 1) asm volatile("s_waitcnt vmcnt(4)" ::: "memory");
    else                 asm volatile("s_waitcnt vmcnt(0)" ::: "memory");
    __builtin_amdgcn_s_barrier();                // all waves' tile-t loads visible
    if (t + 3 < NK) STG1((t + 3) & 3, (t + 3) * 32);   // fire-and-forget prefetch
    const unsigned short* Ac = As + p * 8192;
    const unsigned short* Bc = Bs + p * 8192;
    bf16x8 af[8], bfr[4];
#pragma unroll
    for (int i = 0; i < 8; ++i) {
      int row = wr + i * 16 + l15;
      af[i] = *(const bf16x8*)&Ac[row * 32 + (l4 ^ sx) * 8];
    }
#pragma unroll
    for (int j = 0; j < 4; ++j) {
      int row = wc + j * 16 + l15;
      bfr[j] = *(const bf16x8*)&Bc[row * 32 + (l4 ^ sx) * 8];
    }
    __builtin_amdgcn_s_setprio(1);
#pragma unroll
    for (int i = 0; i < 8; ++i)
#pragma unroll
      for (int j = 0; j < 4; ++j)
        acc[i][j] = __builtin_amdgcn_mfma_f32_16x16x32_bf16(af[i], bfr[j], acc[i][j], 0, 0, 0);
    __builtin_amdgcn_s_setprio(0);
  }
#undef STG1

  // epilogue: frag pair (2p, 2p+1) = (U, G) for one 16-col H block
  const float is2 = 0.70710678118654752f;
  int cb = ((n0 + wc) >> 1);
#pragma unroll
  for (int i = 0; i < 8; ++i) {
    int row = base + wr + i * 16 + l4 * 4;
#pragma unroll
    for (int p = 0; p < 2; ++p) {
      int col = cb + p * 16 + l15;
#pragma unroll
      for (int r = 0; r < 4; ++r) {
        float u = acc[i][2 * p][r], g = acc[i][2 * p + 1][r];
        float gl = 0.5f * g * (1.0f + erff(g * is2));
        H[(size_t)(row + r) * I_DIM + col] = f2bf(u * gl);
      }
    }
  }
}

// -------- 5) GEMM2 (CONTROL, 2-phase dbuf BK=64): 256x256, counted vmcnt ------
__global__ __launch_bounds__(512, 2) void gemm2_kernel(
    const unsigned short* __restrict__ H, const unsigned short* __restrict__ Dt,
    const unsigned short* __restrict__ sDt, unsigned short* __restrict__ Y,
    const int* __restrict__ meta) {
  int orig = blockIdx.x;
  int wg = (orig & 7) * (GRID_G / 8) + (orig >> 3);
  int mt = wg >> 2, nt = wg & 3;
  int2 m2 = ((const int2*)meta)[mt];
  int e = m2.x;
  if (e < 0) return;
  int base = m2.y;
  int n0 = nt * 256;
  const unsigned short* B = (e < E_EXP) ? Dt + (size_t)e * D_DIM * I_DIM : sDt;

  __shared__ unsigned short As[2 * 256 * 64];
  __shared__ unsigned short Bs[2 * 256 * 64];

  int tid = threadIdx.x, lane = tid & 63, wv = tid >> 6;
  const unsigned short *gA[4], *gB[4];
  int dL[4];
#pragma unroll
  for (int j = 0; j < 4; ++j) {
    int c = j * 512 + tid;
    int row = c >> 3, q = c & 7, qs = q ^ (row & 7);
    gA[j] = H + (size_t)(base + row) * I_DIM + qs * 8;
    gB[j] = B + (size_t)(n0 + row) * I_DIM + qs * 8;
    dL[j] = (j * 512 + wv * 64) * 8;
  }

  f32x4 acc[8][4] = {};
  int wr = (wv >> 2) * 128, wc = (wv & 3) * 64;
  int l15 = lane & 15, l4 = lane >> 4;
  int sx = l15 & 7;

#define STAGE2(buf, k0) do { \
  _Pragma("unroll") \
  for (int j = 0; j < 4; ++j) { \
    gload_lds16(gA[j] + (k0), As + (buf) * 16384 + dL[j]); \
    gload_lds16(gB[j] + (k0), Bs + (buf) * 16384 + dL[j]); \
  } } while (0)

  STAGE2(0, 0);
  const int NK = I_DIM / 64;                     // 8
  for (int t = 0; t < NK; ++t) {
    int cur = t & 1;
    if (t + 1 < NK) {
      STAGE2(cur ^ 1, (t + 1) * 64);
      asm volatile("s_waitcnt vmcnt(8)" ::: "memory");
    } else {
      asm volatile("s_waitcnt vmcnt(0)" ::: "memory");
    }
    __builtin_amdgcn_s_barrier();
#pragma unroll
    for (int kh = 0; kh < 2; ++kh) {
      int kb = kh * 4 + l4;
      bf16x8 af[8], bfr[4];
#pragma unroll
      for (int i = 0; i < 8; ++i)
        af[i] = *(const bf16x8*)&As[cur * 16384 + (wr + i * 16 + l15) * 64 + ((kb ^ sx)) * 8];
#pragma unroll
      for (int j = 0; j < 4; ++j)
        bfr[j] = *(const bf16x8*)&Bs[cur * 16384 + (wc + j * 16 + l15) * 64 + ((kb ^ sx)) * 8];
      __builtin_amdgcn_s_setprio(1);
#pragma unroll
      for (int i = 0; i < 8; ++i)
#pragma unroll
        for (int j = 0; j < 4; ++j)
          acc[i][j] = __builtin_amdgcn_mfma_f32_16x16x32_bf16(af[i], bfr[j], acc[i][j], 0, 0, 0);
      __builtin_amdgcn_s_setprio(0);
    }
    asm volatile("" ::: "memory");
    __builtin_amdgcn_s_barrier();
  }
#undef STAGE2

#pragma unroll
  for (int i = 0; i < 8; ++i) {
    int row = base + wr + i * 16 + l4 * 4;
#pragma unroll
    for (int j = 0; j < 4; ++j) {
      int col = n0 + wc + j * 16 + l15;
#pragma unroll
      for (int r = 0; r < 4; ++r)
        Y[(size_t)(row + r) * D_DIM + col] = f2bf(acc[i][j][r]);
    }
  }
}

// ---------------- 6) combine: out = w0*Y[r0] + w1*Y[r1] + Y[shared] ----------------
__global__ void combine_kernel(const unsigned short* __restrict__ Y, const int* __restrict__ inv,
                               const float* __restrict__ tw, float* __restrict__ out) {
  int g = blockIdx.x * 256 + threadIdx.x;
  int t = g >> 7, d0 = (g & 127) * 8;
  int r0 = inv[2 * t], r1 = inv[2 * t + 1];
  float w0 = tw[2 * t], w1 = tw[2 * t + 1];
  ushort8 y0 = *(const ushort8*)&Y[(size_t)r0 * D_DIM + d0];
  ushort8 y1 = *(const ushort8*)&Y[(size_t)r1 * D_DIM + d0];
  ushort8 ys = *(const ushort8*)&Y[(size_t)(SHARED_BASE + t) * D_DIM + d0];
  float o[8];
#pragma unroll
  for (int j = 0; j < 8; ++j)
    o[j] = w0 * bf2f(y0[j]) + w1 * bf2f(y1[j]) + bf2f(ys[j]);
  float4* op = (float4*)(out + (size_t)t * D_DIM + d0);
  op[0] = make_float4(o[0], o[1], o[2], o[3]);
  op[1] = make_float4(o[4], o[5], o[6], o[7]);
}

// ---------------- launcher ----------------
extern "C" void kernel_launch(void* const* d_in, const int* in_sizes, int n_in,
                              void* d_out, int out_size, void* d_ws, size_t ws_size,
                              hipStream_t stream) {
  const float* x    = (const float*)d_in[0];
  const float* gw   = (const float*)d_in[1];
  const float* upw  = (const float*)d_in[2];
  const float* gpw  = (const float*)d_in[3];
  const float* dww  = (const float*)d_in[4];
  const float* sup  = (const float*)d_in[5];
  const float* sgt  = (const float*)d_in[6];
  const float* sdw  = (const float*)d_in[7];
  float* out = (float*)d_out;

  char* ws = (char*)d_ws;
  unsigned short* xb  = (unsigned short*)(ws + OFF_XB);
  unsigned short* UG  = (unsigned short*)(ws + OFF_UG);
  unsigned short* Dt  = (unsigned short*)(ws + OFF_DT);
  unsigned short* sUG = (unsigned short*)(ws + OFF_SUG);
  unsigned short* sDt = (unsigned short*)(ws + OFF_SDT);
  unsigned short* H   = (unsigned short*)(ws + OFF_H);
  unsigned short* Y   = (unsigned short*)(ws + OFF_Y);
  int*   tki   = (int*)(ws + OFF_TOPKI);
  float* tkw   = (float*)(ws + OFF_TOPKW);
  int*   inv   = (int*)(ws + OFF_INV);
  int*   perm  = (int*)(ws + OFF_PERM);
  int*   meta  = (int*)(ws + OFF_META);

  transpose_cvt_all<<<13824, dim3(32, 8), 0, stream>>>(upw, gpw, dww, sup, sgt, sdw,
                                                       UG, sUG, Dt, sDt);
  gating_kernel<<<T_TOK / 4, 256, 0, stream>>>(x, gw, xb, tki, tkw);
  route_kernel<<<1, 1024, 0, stream>>>(tki, meta, perm, inv);

  gemm1_kernel<<<GRID_G, 512, 0, stream>>>(xb, UG, sUG, H, meta, perm);
  gemm2_kernel<<<GRID_G, 512, 0, stream>>>(H, Dt, sDt, Y, meta);
  combine_kernel<<<(T_TOK * 128) / 256, 256, 0, stream>>>(Y, inv, tkw, out);
}

// Round 10
// 115.097 us; speedup vs baseline: 1.0780x; 1.0316x over previous
//
#include <hip/hip_runtime.h>
#include <hip/hip_bf16.h>
#include <math.h>

// ---------------- problem constants ----------------
#define T_TOK 4096
#define D_DIM 1024
#define I_DIM 512
#define E_EXP 8
#define KSEL 2
#define NPAIR (T_TOK * KSEL)          // 8192
#define ROUTED_CAP 10240              // >= 8192 + 7*255, multiple of 256 (40 tiles)
#define SHARED_BASE ROUTED_CAP        // 10240
#define RTOT (ROUTED_CAP + T_TOK)     // 14336
#define MAXTILES 56                   // <= 39 routed + 16 shared + slack
#define GRID_G (MAXTILES * 4)         // 224 = 8 XCDs x 28

typedef __bf16 bf16x8 __attribute__((ext_vector_type(8)));
typedef float f32x4 __attribute__((ext_vector_type(4)));
typedef unsigned short ushort8 __attribute__((ext_vector_type(8)));

// ---------------- scratch layout (bytes) ----------------
constexpr size_t SZ_XB  = (size_t)T_TOK * D_DIM * 2;
constexpr size_t SZ_UG  = (size_t)E_EXP * 2 * I_DIM * D_DIM * 2;
constexpr size_t SZ_DT  = (size_t)E_EXP * I_DIM * D_DIM * 2;
constexpr size_t SZ_SUG = (size_t)2 * I_DIM * D_DIM * 2;
constexpr size_t SZ_SDT = (size_t)I_DIM * D_DIM * 2;
constexpr size_t SZ_H   = (size_t)RTOT * I_DIM * 2;
constexpr size_t SZ_Y   = (size_t)RTOT * D_DIM * 2;

constexpr size_t OFF_XB   = 0;
constexpr size_t OFF_UG   = OFF_XB  + SZ_XB;
constexpr size_t OFF_DT   = OFF_UG  + SZ_UG;
constexpr size_t OFF_SUG  = OFF_DT  + SZ_DT;
constexpr size_t OFF_SDT  = OFF_SUG + SZ_SUG;
constexpr size_t OFF_H    = OFF_SDT + SZ_SDT;
constexpr size_t OFF_Y    = OFF_H   + SZ_H;
constexpr size_t OFF_TOPKI= OFF_Y   + SZ_Y;
constexpr size_t OFF_TOPKW= OFF_TOPKI + (size_t)NPAIR * 4;
constexpr size_t OFF_INV  = OFF_TOPKW + (size_t)NPAIR * 4;
constexpr size_t OFF_PERM = OFF_INV   + (size_t)NPAIR * 4;
constexpr size_t OFF_META = OFF_PERM  + (size_t)RTOT * 4;

// ---------------- helpers ----------------
__device__ __forceinline__ unsigned short f2bf(float f) {
  unsigned int u = __float_as_uint(f);
  unsigned int r = (u + 0x7FFFu + ((u >> 16) & 1u)) >> 16;
  return (unsigned short)r;
}
__device__ __forceinline__ float bf2f(unsigned short s) {
  return __uint_as_float(((unsigned int)s) << 16);
}
__device__ __forceinline__ void gload_lds16(const void* g, void* l) {
  __builtin_amdgcn_global_load_lds(
      (const __attribute__((address_space(1))) void*)g,
      (__attribute__((address_space(3))) void*)l, 16, 0, 0);
}

// ---------------- 1) merged transpose-convert of ALL weights --------------
__global__ void transpose_cvt_all(
    const float* __restrict__ upw, const float* __restrict__ gpw,
    const float* __restrict__ dww, const float* __restrict__ sup,
    const float* __restrict__ sgt, const float* __restrict__ sdw,
    unsigned short* __restrict__ UG, unsigned short* __restrict__ sUG,
    unsigned short* __restrict__ Dt, unsigned short* __restrict__ sDt) {
  __shared__ float t[32][33];
  int bid = blockIdx.x;
  const float* in; unsigned short* out;
  int R, C, xt, yt, mode;
  if (bid < 4096)       { int e = bid >> 9, s = bid & 511;
    in = upw + (size_t)e * D_DIM * I_DIM; out = UG + (size_t)e * 2 * I_DIM * D_DIM;
    R = D_DIM; C = I_DIM; xt = s & 15; yt = s >> 4; mode = 0; }
  else if (bid < 8192)  { int b = bid - 4096; int e = b >> 9, s = b & 511;
    in = gpw + (size_t)e * D_DIM * I_DIM; out = UG + (size_t)e * 2 * I_DIM * D_DIM;
    R = D_DIM; C = I_DIM; xt = s & 15; yt = s >> 4; mode = 1; }
  else if (bid < 12288) { int b = bid - 8192; int e = b >> 9, s = b & 511;
    in = dww + (size_t)e * I_DIM * D_DIM; out = Dt + (size_t)e * I_DIM * D_DIM;
    R = I_DIM; C = D_DIM; xt = s & 31; yt = s >> 5; mode = 2; }
  else if (bid < 12800) { int s = bid - 12288;
    in = sup; out = sUG; R = D_DIM; C = I_DIM; xt = s & 15; yt = s >> 4; mode = 0; }
  else if (bid < 13312) { int s = bid - 12800;
    in = sgt; out = sUG; R = D_DIM; C = I_DIM; xt = s & 15; yt = s >> 4; mode = 1; }
  else                  { int s = bid - 13312;
    in = sdw; out = sDt; R = I_DIM; C = D_DIM; xt = s & 31; yt = s >> 5; mode = 2; }
  int c0 = xt * 32, r0 = yt * 32;
  int tx = threadIdx.x, ty = threadIdx.y;          // block (32,8)
#pragma unroll
  for (int i = 0; i < 4; ++i)
    t[ty + 8 * i][tx] = in[(size_t)(r0 + ty + 8 * i) * C + c0 + tx];
  __syncthreads();
#pragma unroll
  for (int i = 0; i < 4; ++i) {
    int c = c0 + ty + 8 * i;
    int orow = (mode == 2) ? c : (((c >> 4) << 5) + (c & 15) + (mode == 1 ? 16 : 0));
    out[(size_t)orow * R + r0 + tx] = f2bf(t[tx][ty + 8 * i]);
  }
}

// ---------------- 2) gating (+ fused x->bf16): logits, top-2, renorm ----------
__global__ void gating_kernel(const float* __restrict__ x, const float* __restrict__ gw,
                              unsigned short* __restrict__ xb,
                              int* __restrict__ topk_idx, float* __restrict__ topk_w) {
  int lane = threadIdx.x & 63;
  int t = blockIdx.x * 4 + (threadIdx.x >> 6);     // wave per token
  const float4* xr = (const float4*)(x + (size_t)t * D_DIM);
  float4 xv[4];
#pragma unroll
  for (int j = 0; j < 4; ++j) xv[j] = xr[lane + 64 * j];
#pragma unroll
  for (int j = 0; j < 4; ++j) {
    ushort4 o;
    o.x = f2bf(xv[j].x); o.y = f2bf(xv[j].y); o.z = f2bf(xv[j].z); o.w = f2bf(xv[j].w);
    *(ushort4*)&xb[(size_t)t * D_DIM + (lane + 64 * j) * 4] = o;
  }
  float acc[E_EXP];
#pragma unroll
  for (int e = 0; e < E_EXP; ++e) {
    const float4* gr = (const float4*)(gw + (size_t)e * D_DIM);
    float a = 0.f;
#pragma unroll
    for (int j = 0; j < 4; ++j) {
      float4 g = gr[lane + 64 * j];
      a += xv[j].x * g.x + xv[j].y * g.y + xv[j].z * g.z + xv[j].w * g.w;
    }
    acc[e] = a;
  }
#pragma unroll
  for (int off = 32; off; off >>= 1)
#pragma unroll
    for (int e = 0; e < E_EXP; ++e) acc[e] += __shfl_xor(acc[e], off, 64);
  if (lane == 0) {
    int i0 = 0; float m0 = acc[0];
#pragma unroll
    for (int e = 1; e < E_EXP; ++e) if (acc[e] > m0) { m0 = acc[e]; i0 = e; }
    int i1 = -1; float m1 = -1e30f;
#pragma unroll
    for (int e = 0; e < E_EXP; ++e) if (e != i0 && acc[e] > m1) { m1 = acc[e]; i1 = e; }
    float e1 = __expf(m1 - m0);
    float w0 = 1.0f / (1.0f + e1);
    float w1 = e1 / (1.0f + e1);
    topk_idx[2 * t] = i0; topk_idx[2 * t + 1] = i1;
    topk_w[2 * t] = w0;   topk_w[2 * t + 1] = w1;
  }
}

// ---------------- 3) route: counts+offsets+meta+perm+inv, zero atomics --------
__global__ __launch_bounds__(1024) void route_kernel(
    const int* __restrict__ tidx, int* __restrict__ meta,
    int* __restrict__ perm, int* __restrict__ inv) {
  __shared__ int els[NPAIR];            // 32 KB
  __shared__ int cnt_iw[128][E_EXP];
  __shared__ int base_iw[128][E_EXP];
  __shared__ int ebase[E_EXP];
  __shared__ int ecnt[E_EXP];
  int tid = threadIdx.x, lane = tid & 63, wv = tid >> 6;   // 16 waves

  for (int it = 0; it < NPAIR / 1024; ++it) {              // 8 iters
    int g = it * 1024 + tid;
    int e = tidx[g];
    els[g] = e;
#pragma unroll
    for (int ex = 0; ex < E_EXP; ++ex) {
      unsigned long long m = __ballot(e == ex);
      if (lane == 0) cnt_iw[it * 16 + wv][ex] = __popcll(m);
    }
  }
  __syncthreads();

  if (tid < E_EXP) {
    int s = 0;
    for (int iw = 0; iw < 128; ++iw) { base_iw[iw][tid] = s; s += cnt_iw[iw][tid]; }
    ecnt[tid] = s;
  }
  __syncthreads();

  if (tid == 0) {
    int o = 0, tc = 0;
    int2* m2 = (int2*)meta;
    for (int e = 0; e < E_EXP; ++e) {
      ebase[e] = o;
      int c = ecnt[e];
      int pt = (c + 255) >> 8;
      for (int ti = 0; ti < pt; ++ti) m2[tc++] = make_int2(e, o + ti * 256);
      o += pt * 256;
    }
    for (int ti = 0; ti < T_TOK / 256; ++ti)
      m2[tc++] = make_int2(E_EXP, SHARED_BASE + ti * 256);
    for (; tc < MAXTILES; ++tc) m2[tc] = make_int2(-1, 0);
  }
  __syncthreads();

  for (int it = 0; it < NPAIR / 1024; ++it) {
    int g = it * 1024 + tid;
    int e = els[g];
    int rank = 0;
#pragma unroll
    for (int ex = 0; ex < E_EXP; ++ex) {
      unsigned long long m = __ballot(e == ex);
      if (e == ex) rank = __popcll(m & ((1ull << lane) - 1ull));
    }
    int row = ebase[e] + base_iw[it * 16 + wv][e] + rank;
    perm[row] = g >> 1;
    inv[g] = row;
  }
  for (int p = tid; p < E_EXP * 256; p += 1024) {          // pad rows -> token 0
    int e = p >> 8, s = p & 255;
    int c = ecnt[e];
    int padn = (((c + 255) >> 8) << 8) - c;
    if (s < padn) perm[ebase[e] + c + s] = 0;
  }
  for (int t = tid; t < T_TOK; t += 1024) perm[SHARED_BASE + t] = t;
}

// -------- 4) GEMM1 (ARM): R6 staging + within-tile 4-phase ds/MFMA interleave -
// Stage-all-8 at tile start (full-tile prefetch lead, vmcnt(8)); compute split
// into 4 phases: {ds_read subtile BEFORE entry barrier -> barrier -> lgkmcnt(0)
// -> setprio MFMA (acc half) -> barrier}. Reads of phase p drain while phase
// p-1's MFMAs retire; phases alternate acc[0-3]/acc[4-7] so no acc stall.
__global__ __launch_bounds__(512, 2) void gemm1_kernel(
    const unsigned short* __restrict__ xb, const unsigned short* __restrict__ UG,
    const unsigned short* __restrict__ sUG, unsigned short* __restrict__ H,
    const int* __restrict__ meta, const int* __restrict__ perm) {
  int orig = blockIdx.x;
  int wg = (orig & 7) * (GRID_G / 8) + (orig >> 3);  // XCD chunk swizzle (bijective)
  int mt = wg >> 2, nt = wg & 3;
  int2 m2 = ((const int2*)meta)[mt];
  int e = m2.x;
  if (e < 0) return;
  int base = m2.y;
  int n0 = nt * 256;
  const unsigned short* B = (e < E_EXP) ? UG + (size_t)e * 2 * I_DIM * D_DIM : sUG;

  __shared__ unsigned short As[2 * 256 * 64];   // 64 KB (dbuf)
  __shared__ unsigned short Bs[2 * 256 * 64];   // 64 KB

  int tid = threadIdx.x, lane = tid & 63, wv = tid >> 6;   // 8 waves
  const unsigned short *gA[4], *gB[4];
  int dL[4];
#pragma unroll
  for (int j = 0; j < 4; ++j) {
    int c = j * 512 + tid;
    int row = c >> 3, q = c & 7, qs = q ^ (row & 7);
    int tok = perm[base + row];
    gA[j] = xb + (size_t)tok * D_DIM + qs * 8;
    gB[j] = B + (size_t)(n0 + row) * D_DIM + qs * 8;
    dL[j] = (j * 512 + wv * 64) * 8;             // wave-uniform 16B-linear dest
  }

  f32x4 acc[8][4] = {};
  int wr = (wv >> 2) * 128, wc = (wv & 3) * 64;  // 2x4 wave grid, 128x64 each
  int l15 = lane & 15, l4 = lane >> 4;
  int sx = l15 & 7;                              // read-side XOR term

#define STAGE1(buf, k0) do { \
  _Pragma("unroll") \
  for (int j = 0; j < 4; ++j) { \
    gload_lds16(gA[j] + (k0), As + (buf) * 16384 + dL[j]); \
    gload_lds16(gB[j] + (k0), Bs + (buf) * 16384 + dL[j]); \
  } } while (0)

#define MFMA16_1(lo) do { \
    asm volatile("s_waitcnt lgkmcnt(0)" ::: "memory"); \
    __builtin_amdgcn_sched_barrier(0); \
    __builtin_amdgcn_s_setprio(1); \
    _Pragma("unroll") \
    for (int i = 0; i < 4; ++i) \
      _Pragma("unroll") \
      for (int j = 0; j < 4; ++j) \
        acc[(lo) + i][j] = __builtin_amdgcn_mfma_f32_16x16x32_bf16(af[i], bfr[j], acc[(lo) + i][j], 0, 0, 0); \
    __builtin_amdgcn_s_setprio(0); \
    __builtin_amdgcn_s_barrier(); } while (0)

  STAGE1(0, 0);                                  // prologue: full tile 0
  const int NK = D_DIM / 64;                     // 16
  for (int t = 0; t < NK; ++t) {
    int cur = t & 1;
    if (t + 1 < NK) {
      STAGE1(cur ^ 1, (t + 1) * 64);             // full-tile prefetch (8 loads)
      asm volatile("s_waitcnt vmcnt(8)" ::: "memory");   // tile t resident
    } else {
      asm volatile("s_waitcnt vmcnt(0)" ::: "memory");
    }
    __builtin_amdgcn_s_barrier();                // tile entry: buf cur visible
    const unsigned short* Ac = As + cur * 16384;
    const unsigned short* Bc = Bs + cur * 16384;
    bf16x8 af[4], bfr[4];
    int kb0 = l4 ^ sx, kb1 = (4 + l4) ^ sx;
    // phase 0: bfr kh0 + af rows0-3  (reads BEFORE entry barrier)
#pragma unroll
    for (int j = 0; j < 4; ++j) bfr[j] = *(const bf16x8*)&Bc[(wc + j * 16 + l15) * 64 + kb0 * 8];
#pragma unroll
    for (int i = 0; i < 4; ++i) af[i] = *(const bf16x8*)&Ac[(wr + i * 16 + l15) * 64 + kb0 * 8];
    __builtin_amdgcn_s_barrier();
    MFMA16_1(0);
    // phase 1: af rows4-7 kh0 (bfr reused)
#pragma unroll
    for (int i = 0; i < 4; ++i) af[i] = *(const bf16x8*)&Ac[(wr + (4 + i) * 16 + l15) * 64 + kb0 * 8];
    __builtin_amdgcn_s_barrier();
    MFMA16_1(4);
    // phase 2: bfr kh1 + af rows0-3 kh1
#pragma unroll
    for (int j = 0; j < 4; ++j) bfr[j] = *(const bf16x8*)&Bc[(wc + j * 16 + l15) * 64 + kb1 * 8];
#pragma unroll
    for (int i = 0; i < 4; ++i) af[i] = *(const bf16x8*)&Ac[(wr + i * 16 + l15) * 64 + kb1 * 8];
    __builtin_amdgcn_s_barrier();
    MFMA16_1(0);
    // phase 3: af rows4-7 kh1
#pragma unroll
    for (int i = 0; i < 4; ++i) af[i] = *(const bf16x8*)&Ac[(wr + (4 + i) * 16 + l15) * 64 + kb1 * 8];
    __builtin_amdgcn_s_barrier();
    MFMA16_1(4);                                 // exit barrier protects WAR
  }
#undef STAGE1
#undef MFMA16_1

  // epilogue: frag pair (2p, 2p+1) = (U, G) for one 16-col H block
  const float is2 = 0.70710678118654752f;
  int cb = ((n0 + wc) >> 1);
#pragma unroll
  for (int i = 0; i < 8; ++i) {
    int row = base + wr + i * 16 + l4 * 4;
#pragma unroll
    for (int p = 0; p < 2; ++p) {
      int col = cb + p * 16 + l15;
#pragma unroll
      for (int r = 0; r < 4; ++r) {
        float u = acc[i][2 * p][r], g = acc[i][2 * p + 1][r];
        float gl = 0.5f * g * (1.0f + erff(g * is2));
        H[(size_t)(row + r) * I_DIM + col] = f2bf(u * gl);
      }
    }
  }
}

// -------- 5) GEMM2 (CONTROL, exact R6 2-phase dbuf BK=64) ---------
__global__ __launch_bounds__(512, 2) void gemm2_kernel(
    const unsigned short* __restrict__ H, const unsigned short* __restrict__ Dt,
    const unsigned short* __restrict__ sDt, unsigned short* __restrict__ Y,
    const int* __restrict__ meta) {
  int orig = blockIdx.x;
  int wg = (orig & 7) * (GRID_G / 8) + (orig >> 3);
  int mt = wg >> 2, nt = wg & 3;
  int2 m2 = ((const int2*)meta)[mt];
  int e = m2.x;
  if (e < 0) return;
  int base = m2.y;
  int n0 = nt * 256;
  const unsigned short* B = (e < E_EXP) ? Dt + (size_t)e * D_DIM * I_DIM : sDt;

  __shared__ unsigned short As[2 * 256 * 64];
  __shared__ unsigned short Bs[2 * 256 * 64];

  int tid = threadIdx.x, lane = tid & 63, wv = tid >> 6;
  const unsigned short *gA[4], *gB[4];
  int dL[4];
#pragma unroll
  for (int j = 0; j < 4; ++j) {
    int c = j * 512 + tid;
    int row = c >> 3, q = c & 7, qs = q ^ (row & 7);
    gA[j] = H + (size_t)(base + row) * I_DIM + qs * 8;
    gB[j] = B + (size_t)(n0 + row) * I_DIM + qs * 8;
    dL[j] = (j * 512 + wv * 64) * 8;
  }

  f32x4 acc[8][4] = {};
  int wr = (wv >> 2) * 128, wc = (wv & 3) * 64;
  int l15 = lane & 15, l4 = lane >> 4;
  int sx = l15 & 7;

#define STAGE2(buf, k0) do { \
  _Pragma("unroll") \
  for (int j = 0; j < 4; ++j) { \
    gload_lds16(gA[j] + (k0), As + (buf) * 16384 + dL[j]); \
    gload_lds16(gB[j] + (k0), Bs + (buf) * 16384 + dL[j]); \
  } } while (0)

  STAGE2(0, 0);
  const int NK = I_DIM / 64;                     // 8
  for (int t = 0; t < NK; ++t) {
    int cur = t & 1;
    if (t + 1 < NK) {
      STAGE2(cur ^ 1, (t + 1) * 64);
      asm volatile("s_waitcnt vmcnt(8)" ::: "memory");
    } else {
      asm volatile("s_waitcnt vmcnt(0)" ::: "memory");
    }
    __builtin_amdgcn_s_barrier();
#pragma unroll
    for (int kh = 0; kh < 2; ++kh) {
      int kb = kh * 4 + l4;
      bf16x8 af[8], bfr[4];
#pragma unroll
      for (int i = 0; i < 8; ++i)
        af[i] = *(const bf16x8*)&As[cur * 16384 + (wr + i * 16 + l15) * 64 + ((kb ^ sx)) * 8];
#pragma unroll
      for (int j = 0; j < 4; ++j)
        bfr[j] = *(const bf16x8*)&Bs[cur * 16384 + (wc + j * 16 + l15) * 64 + ((kb ^ sx)) * 8];
      __builtin_amdgcn_s_setprio(1);
#pragma unroll
      for (int i = 0; i < 8; ++i)
#pragma unroll
        for (int j = 0; j < 4; ++j)
          acc[i][j] = __builtin_amdgcn_mfma_f32_16x16x32_bf16(af[i], bfr[j], acc[i][j], 0, 0, 0);
      __builtin_amdgcn_s_setprio(0);
    }
    asm volatile("" ::: "memory");
    __builtin_amdgcn_s_barrier();
  }
#undef STAGE2

#pragma unroll
  for (int i = 0; i < 8; ++i) {
    int row = base + wr + i * 16 + l4 * 4;
#pragma unroll
    for (int j = 0; j < 4; ++j) {
      int col = n0 + wc + j * 16 + l15;
#pragma unroll
      for (int r = 0; r < 4; ++r)
        Y[(size_t)(row + r) * D_DIM + col] = f2bf(acc[i][j][r]);
    }
  }
}

// ---------------- 6) combine: out = w0*Y[r0] + w1*Y[r1] + Y[shared] ----------------
__global__ void combine_kernel(const unsigned short* __restrict__ Y, const int* __restrict__ inv,
                               const float* __restrict__ tw, float* __restrict__ out) {
  int g = blockIdx.x * 256 + threadIdx.x;
  int t = g >> 7, d0 = (g & 127) * 8;
  int r0 = inv[2 * t], r1 = inv[2 * t + 1];
  float w0 = tw[2 * t], w1 = tw[2 * t + 1];
  ushort8 y0 = *(const ushort8*)&Y[(size_t)r0 * D_DIM + d0];
  ushort8 y1 = *(const ushort8*)&Y[(size_t)r1 * D_DIM + d0];
  ushort8 ys = *(const ushort8*)&Y[(size_t)(SHARED_BASE + t) * D_DIM + d0];
  float o[8];
#pragma unroll
  for (int j = 0; j < 8; ++j)
    o[j] = w0 * bf2f(y0[j]) + w1 * bf2f(y1[j]) + bf2f(ys[j]);
  float4* op = (float4*)(out + (size_t)t * D_DIM + d0);
  op[0] = make_float4(o[0], o[1], o[2], o[3]);
  op[1] = make_float4(o[4], o[5], o[6], o[7]);
}

// ---------------- launcher ----------------
extern "C" void kernel_launch(void* const* d_in, const int* in_sizes, int n_in,
                              void* d_out, int out_size, void* d_ws, size_t ws_size,
                              hipStream_t stream) {
  const float* x    = (const float*)d_in[0];
  const float* gw   = (const float*)d_in[1];
  const float* upw  = (const float*)d_in[2];
  const float* gpw  = (const float*)d_in[3];
  const float* dww  = (const float*)d_in[4];
  const float* sup  = (const float*)d_in[5];
  const float* sgt  = (const float*)d_in[6];
  const float* sdw  = (const float*)d_in[7];
  float* out = (float*)d_out;

  char* ws = (char*)d_ws;
  unsigned short* xb  = (unsigned short*)(ws + OFF_XB);
  unsigned short* UG  = (unsigned short*)(ws + OFF_UG);
  unsigned short* Dt  = (unsigned short*)(ws + OFF_DT);
  unsigned short* sUG = (unsigned short*)(ws + OFF_SUG);
  unsigned short* sDt = (unsigned short*)(ws + OFF_SDT);
  unsigned short* H   = (unsigned short*)(ws + OFF_H);
  unsigned short* Y   = (unsigned short*)(ws + OFF_Y);
  int*   tki   = (int*)(ws + OFF_TOPKI);
  float* tkw   = (float*)(ws + OFF_TOPKW);
  int*   inv   = (int*)(ws + OFF_INV);
  int*   perm  = (int*)(ws + OFF_PERM);
  int*   meta  = (int*)(ws + OFF_META);

  transpose_cvt_all<<<13824, dim3(32, 8), 0, stream>>>(upw, gpw, dww, sup, sgt, sdw,
                                                       UG, sUG, Dt, sDt);
  gating_kernel<<<T_TOK / 4, 256, 0, stream>>>(x, gw, xb, tki, tkw);
  route_kernel<<<1, 1024, 0, stream>>>(tki, meta, perm, inv);

  gemm1_kernel<<<GRID_G, 512, 0, stream>>>(xb, UG, sUG, H, meta, perm);
  gemm2_kernel<<<GRID_G, 512, 0, stream>>>(H, Dt, sDt, Y, meta);
  combine_kernel<<<(T_TOK * 128) / 256, 256, 0, stream>>>(Y, inv, tkw, out);
}

// Round 11
// 110.219 us; speedup vs baseline: 1.1258x; 1.0443x over previous
//
#include <hip/hip_runtime.h>
#include <hip/hip_bf16.h>
#include <math.h>

// ---------------- problem constants ----------------
#define T_TOK 4096
#define D_DIM 1024
#define I_DIM 512
#define E_EXP 8
#define KSEL 2
#define NPAIR (T_TOK * KSEL)          // 8192
#define ROUTED_CAP 10240              // >= 8192 + 7*255, multiple of 256 (40 tiles)
#define SHARED_BASE ROUTED_CAP        // 10240
#define RTOT (ROUTED_CAP + T_TOK)     // 14336
#define MAXTILES 56                   // <= 39 routed + 16 shared + slack
#define GRID_G (MAXTILES * 4)         // 224 = 8 XCDs x 28

typedef __bf16 bf16x8 __attribute__((ext_vector_type(8)));
typedef float f32x4 __attribute__((ext_vector_type(4)));
typedef unsigned short ushort8 __attribute__((ext_vector_type(8)));

// ---------------- scratch layout (bytes) ----------------
constexpr size_t SZ_XB  = (size_t)T_TOK * D_DIM * 2;
constexpr size_t SZ_UG  = (size_t)E_EXP * 2 * I_DIM * D_DIM * 2;
constexpr size_t SZ_DT  = (size_t)E_EXP * I_DIM * D_DIM * 2;
constexpr size_t SZ_SUG = (size_t)2 * I_DIM * D_DIM * 2;
constexpr size_t SZ_SDT = (size_t)I_DIM * D_DIM * 2;
constexpr size_t SZ_H   = (size_t)RTOT * I_DIM * 2;
constexpr size_t SZ_Y   = (size_t)RTOT * D_DIM * 2;

constexpr size_t OFF_XB   = 0;
constexpr size_t OFF_UG   = OFF_XB  + SZ_XB;
constexpr size_t OFF_DT   = OFF_UG  + SZ_UG;
constexpr size_t OFF_SUG  = OFF_DT  + SZ_DT;
constexpr size_t OFF_SDT  = OFF_SUG + SZ_SUG;
constexpr size_t OFF_H    = OFF_SDT + SZ_SDT;
constexpr size_t OFF_Y    = OFF_H   + SZ_H;
constexpr size_t OFF_TOPKI= OFF_Y   + SZ_Y;
constexpr size_t OFF_TOPKW= OFF_TOPKI + (size_t)NPAIR * 4;
constexpr size_t OFF_INV  = OFF_TOPKW + (size_t)NPAIR * 4;
constexpr size_t OFF_PERM = OFF_INV   + (size_t)NPAIR * 4;
constexpr size_t OFF_META = OFF_PERM  + (size_t)RTOT * 4;

// ---------------- helpers ----------------
__device__ __forceinline__ unsigned short f2bf(float f) {
  unsigned int u = __float_as_uint(f);
  unsigned int r = (u + 0x7FFFu + ((u >> 16) & 1u)) >> 16;
  return (unsigned short)r;
}
__device__ __forceinline__ float bf2f(unsigned short s) {
  return __uint_as_float(((unsigned int)s) << 16);
}
__device__ __forceinline__ void gload_lds16(const void* g, void* l) {
  __builtin_amdgcn_global_load_lds(
      (const __attribute__((address_space(1))) void*)g,
      (__attribute__((address_space(3))) void*)l, 16, 0, 0);
}

// ------- 1) merged transpose-convert, 64x64 tiles (128B write segments) -------
// mode 0: U -> UG interleaved rows ((c>>4)<<5)+(c&15)
// mode 1: G -> UG interleaved rows +16
// mode 2: plain transpose (down weights)
__global__ __launch_bounds__(256) void transpose_cvt64(
    const float* __restrict__ upw, const float* __restrict__ gpw,
    const float* __restrict__ dww, const float* __restrict__ sup,
    const float* __restrict__ sgt, const float* __restrict__ sdw,
    unsigned short* __restrict__ UG, unsigned short* __restrict__ sUG,
    unsigned short* __restrict__ Dt, unsigned short* __restrict__ sDt) {
  __shared__ float t[64][65];                      // 16.6 KB, stride-65 = conflict-free
  int bid = blockIdx.x, tid = threadIdx.x;
  const float* in; unsigned short* out;
  int R, C, xt, yt, mode;
  if (bid < 1024)      { int e = bid >> 7, s = bid & 127;          // U: 16x8 tiles/expert
    in = upw + (size_t)e * D_DIM * I_DIM; out = UG + (size_t)e * 2 * I_DIM * D_DIM;
    R = D_DIM; C = I_DIM; xt = s & 7; yt = s >> 3; mode = 0; }
  else if (bid < 2048) { int b = bid - 1024; int e = b >> 7, s = b & 127;
    in = gpw + (size_t)e * D_DIM * I_DIM; out = UG + (size_t)e * 2 * I_DIM * D_DIM;
    R = D_DIM; C = I_DIM; xt = s & 7; yt = s >> 3; mode = 1; }
  else if (bid < 3072) { int b = bid - 2048; int e = b >> 7, s = b & 127;  // Dw: 8x16
    in = dww + (size_t)e * I_DIM * D_DIM; out = Dt + (size_t)e * I_DIM * D_DIM;
    R = I_DIM; C = D_DIM; xt = s & 15; yt = s >> 4; mode = 2; }
  else if (bid < 3200) { int s = bid - 3072;
    in = sup; out = sUG; R = D_DIM; C = I_DIM; xt = s & 7; yt = s >> 3; mode = 0; }
  else if (bid < 3328) { int s = bid - 3200;
    in = sgt; out = sUG; R = D_DIM; C = I_DIM; xt = s & 7; yt = s >> 3; mode = 1; }
  else                 { int s = bid - 3328;
    in = sdw; out = sDt; R = I_DIM; C = D_DIM; xt = s & 15; yt = s >> 4; mode = 2; }
  int c0 = xt * 64, r0 = yt * 64;
  int tx = tid & 63, ty = tid >> 6;                // (64,4): 256B-coalesced reads
#pragma unroll
  for (int i = 0; i < 16; ++i)
    t[ty + 4 * i][tx] = in[(size_t)(r0 + ty + 4 * i) * C + c0 + tx];
  __syncthreads();
#pragma unroll
  for (int i = 0; i < 16; ++i) {
    int c = c0 + ty + 4 * i;
    int orow = (mode == 2) ? c : (((c >> 4) << 5) + (c & 15) + (mode == 1 ? 16 : 0));
    out[(size_t)orow * R + r0 + tx] = f2bf(t[tx][ty + 4 * i]);   // 128B segments
  }
}

// ---------------- 2) gating (+ fused x->bf16): logits, top-2, renorm ----------
__global__ void gating_kernel(const float* __restrict__ x, const float* __restrict__ gw,
                              unsigned short* __restrict__ xb,
                              int* __restrict__ topk_idx, float* __restrict__ topk_w) {
  int lane = threadIdx.x & 63;
  int t = blockIdx.x * 4 + (threadIdx.x >> 6);     // wave per token
  const float4* xr = (const float4*)(x + (size_t)t * D_DIM);
  float4 xv[4];
#pragma unroll
  for (int j = 0; j < 4; ++j) xv[j] = xr[lane + 64 * j];
#pragma unroll
  for (int j = 0; j < 4; ++j) {
    ushort4 o;
    o.x = f2bf(xv[j].x); o.y = f2bf(xv[j].y); o.z = f2bf(xv[j].z); o.w = f2bf(xv[j].w);
    *(ushort4*)&xb[(size_t)t * D_DIM + (lane + 64 * j) * 4] = o;
  }
  float acc[E_EXP];
#pragma unroll
  for (int e = 0; e < E_EXP; ++e) {
    const float4* gr = (const float4*)(gw + (size_t)e * D_DIM);
    float a = 0.f;
#pragma unroll
    for (int j = 0; j < 4; ++j) {
      float4 g = gr[lane + 64 * j];
      a += xv[j].x * g.x + xv[j].y * g.y + xv[j].z * g.z + xv[j].w * g.w;
    }
    acc[e] = a;
  }
#pragma unroll
  for (int off = 32; off; off >>= 1)
#pragma unroll
    for (int e = 0; e < E_EXP; ++e) acc[e] += __shfl_xor(acc[e], off, 64);
  if (lane == 0) {
    int i0 = 0; float m0 = acc[0];
#pragma unroll
    for (int e = 1; e < E_EXP; ++e) if (acc[e] > m0) { m0 = acc[e]; i0 = e; }
    int i1 = -1; float m1 = -1e30f;
#pragma unroll
    for (int e = 0; e < E_EXP; ++e) if (e != i0 && acc[e] > m1) { m1 = acc[e]; i1 = e; }
    float e1 = __expf(m1 - m0);
    float w0 = 1.0f / (1.0f + e1);
    float w1 = e1 / (1.0f + e1);
    topk_idx[2 * t] = i0; topk_idx[2 * t + 1] = i1;
    topk_w[2 * t] = w0;   topk_w[2 * t + 1] = w1;
  }
}

// ---------------- 3) route: counts+offsets+meta+perm+inv, zero atomics --------
__global__ __launch_bounds__(1024) void route_kernel(
    const int* __restrict__ tidx, int* __restrict__ meta,
    int* __restrict__ perm, int* __restrict__ inv) {
  __shared__ int els[NPAIR];            // 32 KB
  __shared__ int cnt_iw[128][E_EXP];
  __shared__ int base_iw[128][E_EXP];
  __shared__ int ebase[E_EXP];
  __shared__ int ecnt[E_EXP];
  int tid = threadIdx.x, lane = tid & 63, wv = tid >> 6;   // 16 waves

  for (int it = 0; it < NPAIR / 1024; ++it) {              // 8 iters
    int g = it * 1024 + tid;
    int e = tidx[g];
    els[g] = e;
#pragma unroll
    for (int ex = 0; ex < E_EXP; ++ex) {
      unsigned long long m = __ballot(e == ex);
      if (lane == 0) cnt_iw[it * 16 + wv][ex] = __popcll(m);
    }
  }
  __syncthreads();

  if (tid < E_EXP) {
    int s = 0;
    for (int iw = 0; iw < 128; ++iw) { base_iw[iw][tid] = s; s += cnt_iw[iw][tid]; }
    ecnt[tid] = s;
  }
  __syncthreads();

  if (tid == 0) {
    int o = 0, tc = 0;
    int2* m2 = (int2*)meta;
    for (int e = 0; e < E_EXP; ++e) {
      ebase[e] = o;
      int c = ecnt[e];
      int pt = (c + 255) >> 8;
      for (int ti = 0; ti < pt; ++ti) m2[tc++] = make_int2(e, o + ti * 256);
      o += pt * 256;
    }
    for (int ti = 0; ti < T_TOK / 256; ++ti)
      m2[tc++] = make_int2(E_EXP, SHARED_BASE + ti * 256);
    for (; tc < MAXTILES; ++tc) m2[tc] = make_int2(-1, 0);
  }
  __syncthreads();

  for (int it = 0; it < NPAIR / 1024; ++it) {
    int g = it * 1024 + tid;
    int e = els[g];
    int rank = 0;
#pragma unroll
    for (int ex = 0; ex < E_EXP; ++ex) {
      unsigned long long m = __ballot(e == ex);
      if (e == ex) rank = __popcll(m & ((1ull << lane) - 1ull));
    }
    int row = ebase[e] + base_iw[it * 16 + wv][e] + rank;
    perm[row] = g >> 1;
    inv[g] = row;
  }
  for (int p = tid; p < E_EXP * 256; p += 1024) {          // pad rows -> token 0
    int e = p >> 8, s = p & 255;
    int c = ecnt[e];
    int padn = (((c + 255) >> 8) << 8) - c;
    if (s < padn) perm[ebase[e] + c + s] = 0;
  }
  for (int t = tid; t < T_TOK; t += 1024) perm[SHARED_BASE + t] = t;
}

// -------- 4) GEMM1 (R6 exact, best measured): 256x256, 2-phase dbuf ----------
__global__ __launch_bounds__(512, 2) void gemm1_kernel(
    const unsigned short* __restrict__ xb, const unsigned short* __restrict__ UG,
    const unsigned short* __restrict__ sUG, unsigned short* __restrict__ H,
    const int* __restrict__ meta, const int* __restrict__ perm) {
  int orig = blockIdx.x;
  int wg = (orig & 7) * (GRID_G / 8) + (orig >> 3);  // XCD chunk swizzle (bijective)
  int mt = wg >> 2, nt = wg & 3;
  int2 m2 = ((const int2*)meta)[mt];
  int e = m2.x;
  if (e < 0) return;
  int base = m2.y;
  int n0 = nt * 256;
  const unsigned short* B = (e < E_EXP) ? UG + (size_t)e * 2 * I_DIM * D_DIM : sUG;

  __shared__ unsigned short As[2 * 256 * 64];   // 64 KB (dbuf)
  __shared__ unsigned short Bs[2 * 256 * 64];   // 64 KB

  int tid = threadIdx.x, lane = tid & 63, wv = tid >> 6;   // 8 waves
  const unsigned short *gA[4], *gB[4];
  int dL[4];
#pragma unroll
  for (int j = 0; j < 4; ++j) {
    int c = j * 512 + tid;
    int row = c >> 3, q = c & 7, qs = q ^ (row & 7);
    int tok = perm[base + row];
    gA[j] = xb + (size_t)tok * D_DIM + qs * 8;
    gB[j] = B + (size_t)(n0 + row) * D_DIM + qs * 8;
    dL[j] = (j * 512 + wv * 64) * 8;             // wave-uniform 16B-linear dest
  }

  f32x4 acc[8][4] = {};
  int wr = (wv >> 2) * 128, wc = (wv & 3) * 64;  // 2x4 wave grid, 128x64 each
  int l15 = lane & 15, l4 = lane >> 4;
  int sx = l15 & 7;                              // read-side XOR term

#define STAGE1(buf, k0) do { \
  _Pragma("unroll") \
  for (int j = 0; j < 4; ++j) { \
    gload_lds16(gA[j] + (k0), As + (buf) * 16384 + dL[j]); \
    gload_lds16(gB[j] + (k0), Bs + (buf) * 16384 + dL[j]); \
  } } while (0)

  STAGE1(0, 0);                                  // prologue
  const int NK = D_DIM / 64;                     // 16
  for (int t = 0; t < NK; ++t) {
    int cur = t & 1;
    if (t + 1 < NK) {
      STAGE1(cur ^ 1, (t + 1) * 64);
      asm volatile("s_waitcnt vmcnt(8)" ::: "memory");   // only cur's 8 loads
    } else {
      asm volatile("s_waitcnt vmcnt(0)" ::: "memory");
    }
    __builtin_amdgcn_s_barrier();                // buf[cur] visible to all
#pragma unroll
    for (int kh = 0; kh < 2; ++kh) {
      int kb = kh * 4 + l4;
      bf16x8 af[8], bfr[4];
#pragma unroll
      for (int i = 0; i < 8; ++i)
        af[i] = *reinterpret_cast<const bf16x8*>(&As[cur * 16384 + (wr + i * 16 + l15) * 64 + ((kb ^ sx)) * 8]);
#pragma unroll
      for (int j = 0; j < 4; ++j)
        bfr[j] = *reinterpret_cast<const bf16x8*>(&Bs[cur * 16384 + (wc + j * 16 + l15) * 64 + ((kb ^ sx)) * 8]);
      __builtin_amdgcn_s_setprio(1);
#pragma unroll
      for (int i = 0; i < 8; ++i)
#pragma unroll
        for (int j = 0; j < 4; ++j)
          acc[i][j] = __builtin_amdgcn_mfma_f32_16x16x32_bf16(af[i], bfr[j], acc[i][j], 0, 0, 0);
      __builtin_amdgcn_s_setprio(0);
    }
    asm volatile("" ::: "memory");
    __builtin_amdgcn_s_barrier();                // reads done -> next stage safe
  }
#undef STAGE1

  // epilogue: frag pair (2p, 2p+1) = (U, G) for one 16-col H block
  const float is2 = 0.70710678118654752f;
  int cb = ((n0 + wc) >> 1);
#pragma unroll
  for (int i = 0; i < 8; ++i) {
    int row = base + wr + i * 16 + l4 * 4;
#pragma unroll
    for (int p = 0; p < 2; ++p) {
      int col = cb + p * 16 + l15;
#pragma unroll
      for (int r = 0; r < 4; ++r) {
        float u = acc[i][2 * p][r], g = acc[i][2 * p + 1][r];
        float gl = 0.5f * g * (1.0f + erff(g * is2));
        H[(size_t)(row + r) * I_DIM + col] = f2bf(u * gl);
      }
    }
  }
}

// -------- 5) GEMM2 (R6 exact): 256x256, 2-phase dbuf, counted vmcnt ----------
__global__ __launch_bounds__(512, 2) void gemm2_kernel(
    const unsigned short* __restrict__ H, const unsigned short* __restrict__ Dt,
    const unsigned short* __restrict__ sDt, unsigned short* __restrict__ Y,
    const int* __restrict__ meta) {
  int orig = blockIdx.x;
  int wg = (orig & 7) * (GRID_G / 8) + (orig >> 3);
  int mt = wg >> 2, nt = wg & 3;
  int2 m2 = ((const int2*)meta)[mt];
  int e = m2.x;
  if (e < 0) return;
  int base = m2.y;
  int n0 = nt * 256;
  const unsigned short* B = (e < E_EXP) ? Dt + (size_t)e * D_DIM * I_DIM : sDt;

  __shared__ unsigned short As[2 * 256 * 64];
  __shared__ unsigned short Bs[2 * 256 * 64];

  int tid = threadIdx.x, lane = tid & 63, wv = tid >> 6;
  const unsigned short *gA[4], *gB[4];
  int dL[4];
#pragma unroll
  for (int j = 0; j < 4; ++j) {
    int c = j * 512 + tid;
    int row = c >> 3, q = c & 7, qs = q ^ (row & 7);
    gA[j] = H + (size_t)(base + row) * I_DIM + qs * 8;
    gB[j] = B + (size_t)(n0 + row) * I_DIM + qs * 8;
    dL[j] = (j * 512 + wv * 64) * 8;
  }

  f32x4 acc[8][4] = {};
  int wr = (wv >> 2) * 128, wc = (wv & 3) * 64;
  int l15 = lane & 15, l4 = lane >> 4;
  int sx = l15 & 7;

#define STAGE2(buf, k0) do { \
  _Pragma("unroll") \
  for (int j = 0; j < 4; ++j) { \
    gload_lds16(gA[j] + (k0), As + (buf) * 16384 + dL[j]); \
    gload_lds16(gB[j] + (k0), Bs + (buf) * 16384 + dL[j]); \
  } } while (0)

  STAGE2(0, 0);
  const int NK = I_DIM / 64;                     // 8
  for (int t = 0; t < NK; ++t) {
    int cur = t & 1;
    if (t + 1 < NK) {
      STAGE2(cur ^ 1, (t + 1) * 64);
      asm volatile("s_waitcnt vmcnt(8)" ::: "memory");
    } else {
      asm volatile("s_waitcnt vmcnt(0)" ::: "memory");
    }
    __builtin_amdgcn_s_barrier();
#pragma unroll
    for (int kh = 0; kh < 2; ++kh) {
      int kb = kh * 4 + l4;
      bf16x8 af[8], bfr[4];
#pragma unroll
      for (int i = 0; i < 8; ++i)
        af[i] = *reinterpret_cast<const bf16x8*>(&As[cur * 16384 + (wr + i * 16 + l15) * 64 + ((kb ^ sx)) * 8]);
#pragma unroll
      for (int j = 0; j < 4; ++j)
        bfr[j] = *reinterpret_cast<const bf16x8*>(&Bs[cur * 16384 + (wc + j * 16 + l15) * 64 + ((kb ^ sx)) * 8]);
      __builtin_amdgcn_s_setprio(1);
#pragma unroll
      for (int i = 0; i < 8; ++i)
#pragma unroll
        for (int j = 0; j < 4; ++j)
          acc[i][j] = __builtin_amdgcn_mfma_f32_16x16x32_bf16(af[i], bfr[j], acc[i][j], 0, 0, 0);
      __builtin_amdgcn_s_setprio(0);
    }
    asm volatile("" ::: "memory");
    __builtin_amdgcn_s_barrier();
  }
#undef STAGE2

#pragma unroll
  for (int i = 0; i < 8; ++i) {
    int row = base + wr + i * 16 + l4 * 4;
#pragma unroll
    for (int j = 0; j < 4; ++j) {
      int col = n0 + wc + j * 16 + l15;
#pragma unroll
      for (int r = 0; r < 4; ++r)
        Y[(size_t)(row + r) * D_DIM + col] = f2bf(acc[i][j][r]);
    }
  }
}

// ---------------- 6) combine: out = w0*Y[r0] + w1*Y[r1] + Y[shared] ----------------
__global__ void combine_kernel(const unsigned short* __restrict__ Y, const int* __restrict__ inv,
                               const float* __restrict__ tw, float* __restrict__ out) {
  int g = blockIdx.x * 256 + threadIdx.x;
  int t = g >> 7, d0 = (g & 127) * 8;
  int r0 = inv[2 * t], r1 = inv[2 * t + 1];
  float w0 = tw[2 * t], w1 = tw[2 * t + 1];
  ushort8 y0 = *(const ushort8*)&Y[(size_t)r0 * D_DIM + d0];
  ushort8 y1 = *(const ushort8*)&Y[(size_t)r1 * D_DIM + d0];
  ushort8 ys = *(const ushort8*)&Y[(size_t)(SHARED_BASE + t) * D_DIM + d0];
  float o[8];
#pragma unroll
  for (int j = 0; j < 8; ++j)
    o[j] = w0 * bf2f(y0[j]) + w1 * bf2f(y1[j]) + bf2f(ys[j]);
  float4* op = (float4*)(out + (size_t)t * D_DIM + d0);
  op[0] = make_float4(o[0], o[1], o[2], o[3]);
  op[1] = make_float4(o[4], o[5], o[6], o[7]);
}

// ---------------- launcher ----------------
extern "C" void kernel_launch(void* const* d_in, const int* in_sizes, int n_in,
                              void* d_out, int out_size, void* d_ws, size_t ws_size,
                              hipStream_t stream) {
  const float* x    = (const float*)d_in[0];
  const float* gw   = (const float*)d_in[1];
  const float* upw  = (const float*)d_in[2];
  const float* gpw  = (const float*)d_in[3];
  const float* dww  = (const float*)d_in[4];
  const float* sup  = (const float*)d_in[5];
  const float* sgt  = (const float*)d_in[6];
  const float* sdw  = (const float*)d_in[7];
  float* out = (float*)d_out;

  char* ws = (char*)d_ws;
  unsigned short* xb  = (unsigned short*)(ws + OFF_XB);
  unsigned short* UG  = (unsigned short*)(ws + OFF_UG);
  unsigned short* Dt  = (unsigned short*)(ws + OFF_DT);
  unsigned short* sUG = (unsigned short*)(ws + OFF_SUG);
  unsigned short* sDt = (unsigned short*)(ws + OFF_SDT);
  unsigned short* H   = (unsigned short*)(ws + OFF_H);
  unsigned short* Y   = (unsigned short*)(ws + OFF_Y);
  int*   tki   = (int*)(ws + OFF_TOPKI);
  float* tkw   = (float*)(ws + OFF_TOPKW);
  int*   inv   = (int*)(ws + OFF_INV);
  int*   perm  = (int*)(ws + OFF_PERM);
  int*   meta  = (int*)(ws + OFF_META);

  transpose_cvt64<<<3456, 256, 0, stream>>>(upw, gpw, dww, sup, sgt, sdw,
                                            UG, sUG, Dt, sDt);
  gating_kernel<<<T_TOK / 4, 256, 0, stream>>>(x, gw, xb, tki, tkw);
  route_kernel<<<1, 1024, 0, stream>>>(tki, meta, perm, inv);

  gemm1_kernel<<<GRID_G, 512, 0, stream>>>(xb, UG, sUG, H, meta, perm);
  gemm2_kernel<<<GRID_G, 512, 0, stream>>>(H, Dt, sDt, Y, meta);
  combine_kernel<<<(T_TOK * 128) / 256, 256, 0, stream>>>(Y, inv, tkw, out);
}

// Round 12
// 107.941 us; speedup vs baseline: 1.1495x; 1.0211x over previous
//
#include <hip/hip_runtime.h>
#include <hip/hip_bf16.h>
#include <math.h>

// ---------------- problem constants ----------------
#define T_TOK 4096
#define D_DIM 1024
#define I_DIM 512
#define E_EXP 8
#define KSEL 2
#define NPAIR (T_TOK * KSEL)          // 8192
#define ROUTED_CAP 10240              // >= 8192 + 7*255, multiple of 256 (40 tiles)
#define SHARED_BASE ROUTED_CAP        // 10240
#define RTOT (ROUTED_CAP + T_TOK)     // 14336
#define MAXTILES 56                   // <= 39 routed + 16 shared + slack
#define GRID_G (MAXTILES * 4)         // 224 = 8 XCDs x 28
#define NTRB 3456                     // transpose blocks in prep kernel

typedef __bf16 bf16x8 __attribute__((ext_vector_type(8)));
typedef float f32x4 __attribute__((ext_vector_type(4)));
typedef unsigned short ushort8 __attribute__((ext_vector_type(8)));

// ---------------- scratch layout (bytes) ----------------
constexpr size_t SZ_XB  = (size_t)T_TOK * D_DIM * 2;
constexpr size_t SZ_UG  = (size_t)E_EXP * 2 * I_DIM * D_DIM * 2;
constexpr size_t SZ_DT  = (size_t)E_EXP * I_DIM * D_DIM * 2;
constexpr size_t SZ_SUG = (size_t)2 * I_DIM * D_DIM * 2;
constexpr size_t SZ_SDT = (size_t)I_DIM * D_DIM * 2;
constexpr size_t SZ_H   = (size_t)RTOT * I_DIM * 2;
constexpr size_t SZ_Y   = (size_t)RTOT * D_DIM * 2;

constexpr size_t OFF_XB   = 0;
constexpr size_t OFF_UG   = OFF_XB  + SZ_XB;
constexpr size_t OFF_DT   = OFF_UG  + SZ_UG;
constexpr size_t OFF_SUG  = OFF_DT  + SZ_DT;
constexpr size_t OFF_SDT  = OFF_SUG + SZ_SUG;
constexpr size_t OFF_H    = OFF_SDT + SZ_SDT;
constexpr size_t OFF_Y    = OFF_H   + SZ_H;
constexpr size_t OFF_TOPKI= OFF_Y   + SZ_Y;
constexpr size_t OFF_TOPKW= OFF_TOPKI + (size_t)NPAIR * 4;
constexpr size_t OFF_INV  = OFF_TOPKW + (size_t)NPAIR * 4;
constexpr size_t OFF_PERM = OFF_INV   + (size_t)NPAIR * 4;
constexpr size_t OFF_META = OFF_PERM  + (size_t)RTOT * 4;

// ---------------- helpers ----------------
__device__ __forceinline__ unsigned short f2bf(float f) {
  unsigned int u = __float_as_uint(f);
  unsigned int r = (u + 0x7FFFu + ((u >> 16) & 1u)) >> 16;
  return (unsigned short)r;
}
__device__ __forceinline__ float bf2f(unsigned short s) {
  return __uint_as_float(((unsigned int)s) << 16);
}
__device__ __forceinline__ void gload_lds16(const void* g, void* l) {
  __builtin_amdgcn_global_load_lds(
      (const __attribute__((address_space(1))) void*)g,
      (__attribute__((address_space(3))) void*)l, 16, 0, 0);
}

// ------- 1) prep: 64x64 weight transpose-convert + gating (+x->bf16), merged -
// bid < NTRB: transpose tiles. bid >= NTRB: gating blocks (4 tokens each).
__global__ __launch_bounds__(256) void prep_kernel(
    const float* __restrict__ x,   const float* __restrict__ gw,
    const float* __restrict__ upw, const float* __restrict__ gpw,
    const float* __restrict__ dww, const float* __restrict__ sup,
    const float* __restrict__ sgt, const float* __restrict__ sdw,
    unsigned short* __restrict__ UG, unsigned short* __restrict__ sUG,
    unsigned short* __restrict__ Dt, unsigned short* __restrict__ sDt,
    unsigned short* __restrict__ xb,
    int* __restrict__ topk_idx, float* __restrict__ topk_w) {
  __shared__ float t[64][65];                      // 16.6 KB, conflict-free
  int bid = blockIdx.x, tid = threadIdx.x;
  if (bid < NTRB) {
    const float* in; unsigned short* out;
    int R, C, xt, yt, mode;
    if (bid < 1024)      { int e = bid >> 7, s = bid & 127;        // U: 16x8/expert
      in = upw + (size_t)e * D_DIM * I_DIM; out = UG + (size_t)e * 2 * I_DIM * D_DIM;
      R = D_DIM; C = I_DIM; xt = s & 7; yt = s >> 3; mode = 0; }
    else if (bid < 2048) { int b = bid - 1024; int e = b >> 7, s = b & 127;
      in = gpw + (size_t)e * D_DIM * I_DIM; out = UG + (size_t)e * 2 * I_DIM * D_DIM;
      R = D_DIM; C = I_DIM; xt = s & 7; yt = s >> 3; mode = 1; }
    else if (bid < 3072) { int b = bid - 2048; int e = b >> 7, s = b & 127;  // Dw
      in = dww + (size_t)e * I_DIM * D_DIM; out = Dt + (size_t)e * I_DIM * D_DIM;
      R = I_DIM; C = D_DIM; xt = s & 15; yt = s >> 4; mode = 2; }
    else if (bid < 3200) { int s = bid - 3072;
      in = sup; out = sUG; R = D_DIM; C = I_DIM; xt = s & 7; yt = s >> 3; mode = 0; }
    else if (bid < 3328) { int s = bid - 3200;
      in = sgt; out = sUG; R = D_DIM; C = I_DIM; xt = s & 7; yt = s >> 3; mode = 1; }
    else                 { int s = bid - 3328;
      in = sdw; out = sDt; R = I_DIM; C = D_DIM; xt = s & 15; yt = s >> 4; mode = 2; }
    int c0 = xt * 64, r0 = yt * 64;
    int tx = tid & 63, ty = tid >> 6;              // (64,4): 256B-coalesced reads
#pragma unroll
    for (int i = 0; i < 16; ++i)
      t[ty + 4 * i][tx] = in[(size_t)(r0 + ty + 4 * i) * C + c0 + tx];
    __syncthreads();
#pragma unroll
    for (int i = 0; i < 16; ++i) {
      int c = c0 + ty + 4 * i;
      int orow = (mode == 2) ? c : (((c >> 4) << 5) + (c & 15) + (mode == 1 ? 16 : 0));
      out[(size_t)orow * R + r0 + tx] = f2bf(t[tx][ty + 4 * i]);   // 128B segments
    }
  } else {
    int lane = tid & 63;
    int tok = (bid - NTRB) * 4 + (tid >> 6);       // wave per token
    const float4* xr = (const float4*)(x + (size_t)tok * D_DIM);
    float4 xv[4];
#pragma unroll
    for (int j = 0; j < 4; ++j) xv[j] = xr[lane + 64 * j];
#pragma unroll
    for (int j = 0; j < 4; ++j) {
      ushort4 o;
      o.x = f2bf(xv[j].x); o.y = f2bf(xv[j].y); o.z = f2bf(xv[j].z); o.w = f2bf(xv[j].w);
      *(ushort4*)&xb[(size_t)tok * D_DIM + (lane + 64 * j) * 4] = o;
    }
    float acc[E_EXP];
#pragma unroll
    for (int e = 0; e < E_EXP; ++e) {
      const float4* gr = (const float4*)(gw + (size_t)e * D_DIM);
      float a = 0.f;
#pragma unroll
      for (int j = 0; j < 4; ++j) {
        float4 g = gr[lane + 64 * j];
        a += xv[j].x * g.x + xv[j].y * g.y + xv[j].z * g.z + xv[j].w * g.w;
      }
      acc[e] = a;
    }
#pragma unroll
    for (int off = 32; off; off >>= 1)
#pragma unroll
      for (int e = 0; e < E_EXP; ++e) acc[e] += __shfl_xor(acc[e], off, 64);
    if (lane == 0) {
      int i0 = 0; float m0 = acc[0];
#pragma unroll
      for (int e = 1; e < E_EXP; ++e) if (acc[e] > m0) { m0 = acc[e]; i0 = e; }
      int i1 = -1; float m1 = -1e30f;
#pragma unroll
      for (int e = 0; e < E_EXP; ++e) if (e != i0 && acc[e] > m1) { m1 = acc[e]; i1 = e; }
      float e1 = __expf(m1 - m0);
      float w0 = 1.0f / (1.0f + e1);
      float w1 = e1 / (1.0f + e1);
      topk_idx[2 * tok] = i0; topk_idx[2 * tok + 1] = i1;
      topk_w[2 * tok] = w0;   topk_w[2 * tok + 1] = w1;
    }
  }
}

// ---------------- 2) route: counts+offsets+meta+perm+inv, zero atomics --------
__global__ __launch_bounds__(1024) void route_kernel(
    const int* __restrict__ tidx, int* __restrict__ meta,
    int* __restrict__ perm, int* __restrict__ inv) {
  __shared__ int els[NPAIR];            // 32 KB
  __shared__ int cnt_iw[128][E_EXP];
  __shared__ int base_iw[128][E_EXP];
  __shared__ int ebase[E_EXP];
  __shared__ int ecnt[E_EXP];
  int tid = threadIdx.x, lane = tid & 63, wv = tid >> 6;   // 16 waves

  for (int it = 0; it < NPAIR / 1024; ++it) {              // 8 iters
    int g = it * 1024 + tid;
    int e = tidx[g];
    els[g] = e;
#pragma unroll
    for (int ex = 0; ex < E_EXP; ++ex) {
      unsigned long long m = __ballot(e == ex);
      if (lane == 0) cnt_iw[it * 16 + wv][ex] = __popcll(m);
    }
  }
  __syncthreads();

  if (tid < E_EXP) {
    int s = 0;
    for (int iw = 0; iw < 128; ++iw) { base_iw[iw][tid] = s; s += cnt_iw[iw][tid]; }
    ecnt[tid] = s;
  }
  __syncthreads();

  if (tid == 0) {
    int o = 0, tc = 0;
    int2* m2 = (int2*)meta;
    for (int e = 0; e < E_EXP; ++e) {
      ebase[e] = o;
      int c = ecnt[e];
      int pt = (c + 255) >> 8;
      for (int ti = 0; ti < pt; ++ti) m2[tc++] = make_int2(e, o + ti * 256);
      o += pt * 256;
    }
    for (int ti = 0; ti < T_TOK / 256; ++ti)
      m2[tc++] = make_int2(E_EXP, SHARED_BASE + ti * 256);
    for (; tc < MAXTILES; ++tc) m2[tc] = make_int2(-1, 0);
  }
  __syncthreads();

  for (int it = 0; it < NPAIR / 1024; ++it) {
    int g = it * 1024 + tid;
    int e = els[g];
    int rank = 0;
#pragma unroll
    for (int ex = 0; ex < E_EXP; ++ex) {
      unsigned long long m = __ballot(e == ex);
      if (e == ex) rank = __popcll(m & ((1ull << lane) - 1ull));
    }
    int row = ebase[e] + base_iw[it * 16 + wv][e] + rank;
    perm[row] = g >> 1;
    inv[g] = row;
  }
  for (int p = tid; p < E_EXP * 256; p += 1024) {          // pad rows -> token 0
    int e = p >> 8, s = p & 255;
    int c = ecnt[e];
    int padn = (((c + 255) >> 8) << 8) - c;
    if (s < padn) perm[ebase[e] + c + s] = 0;
  }
  for (int t = tid; t < T_TOK; t += 1024) perm[SHARED_BASE + t] = t;
}

// -------- 3) GEMM1 (R6 exact, best measured): 256x256, 2-phase dbuf ----------
__global__ __launch_bounds__(512, 2) void gemm1_kernel(
    const unsigned short* __restrict__ xb, const unsigned short* __restrict__ UG,
    const unsigned short* __restrict__ sUG, unsigned short* __restrict__ H,
    const int* __restrict__ meta, const int* __restrict__ perm) {
  int orig = blockIdx.x;
  int wg = (orig & 7) * (GRID_G / 8) + (orig >> 3);  // XCD chunk swizzle (bijective)
  int mt = wg >> 2, nt = wg & 3;
  int2 m2 = ((const int2*)meta)[mt];
  int e = m2.x;
  if (e < 0) return;
  int base = m2.y;
  int n0 = nt * 256;
  const unsigned short* B = (e < E_EXP) ? UG + (size_t)e * 2 * I_DIM * D_DIM : sUG;

  __shared__ unsigned short As[2 * 256 * 64];   // 64 KB (dbuf)
  __shared__ unsigned short Bs[2 * 256 * 64];   // 64 KB

  int tid = threadIdx.x, lane = tid & 63, wv = tid >> 6;   // 8 waves
  const unsigned short *gA[4], *gB[4];
  int dL[4];
#pragma unroll
  for (int j = 0; j < 4; ++j) {
    int c = j * 512 + tid;
    int row = c >> 3, q = c & 7, qs = q ^ (row & 7);
    int tok = perm[base + row];
    gA[j] = xb + (size_t)tok * D_DIM + qs * 8;
    gB[j] = B + (size_t)(n0 + row) * D_DIM + qs * 8;
    dL[j] = (j * 512 + wv * 64) * 8;             // wave-uniform 16B-linear dest
  }

  f32x4 acc[8][4] = {};
  int wr = (wv >> 2) * 128, wc = (wv & 3) * 64;  // 2x4 wave grid, 128x64 each
  int l15 = lane & 15, l4 = lane >> 4;
  int sx = l15 & 7;                              // read-side XOR term

#define STAGE1(buf, k0) do { \
  _Pragma("unroll") \
  for (int j = 0; j < 4; ++j) { \
    gload_lds16(gA[j] + (k0), As + (buf) * 16384 + dL[j]); \
    gload_lds16(gB[j] + (k0), Bs + (buf) * 16384 + dL[j]); \
  } } while (0)

  STAGE1(0, 0);                                  // prologue
  const int NK = D_DIM / 64;                     // 16
  for (int t = 0; t < NK; ++t) {
    int cur = t & 1;
    if (t + 1 < NK) {
      STAGE1(cur ^ 1, (t + 1) * 64);
      asm volatile("s_waitcnt vmcnt(8)" ::: "memory");   // only cur's 8 loads
    } else {
      asm volatile("s_waitcnt vmcnt(0)" ::: "memory");
    }
    __builtin_amdgcn_s_barrier();                // buf[cur] visible to all
#pragma unroll
    for (int kh = 0; kh < 2; ++kh) {
      int kb = kh * 4 + l4;
      bf16x8 af[8], bfr[4];
#pragma unroll
      for (int i = 0; i < 8; ++i)
        af[i] = *reinterpret_cast<const bf16x8*>(&As[cur * 16384 + (wr + i * 16 + l15) * 64 + ((kb ^ sx)) * 8]);
#pragma unroll
      for (int j = 0; j < 4; ++j)
        bfr[j] = *reinterpret_cast<const bf16x8*>(&Bs[cur * 16384 + (wc + j * 16 + l15) * 64 + ((kb ^ sx)) * 8]);
      __builtin_amdgcn_s_setprio(1);
#pragma unroll
      for (int i = 0; i < 8; ++i)
#pragma unroll
        for (int j = 0; j < 4; ++j)
          acc[i][j] = __builtin_amdgcn_mfma_f32_16x16x32_bf16(af[i], bfr[j], acc[i][j], 0, 0, 0);
      __builtin_amdgcn_s_setprio(0);
    }
    asm volatile("" ::: "memory");
    __builtin_amdgcn_s_barrier();                // reads done -> next stage safe
  }
#undef STAGE1

  // epilogue: frag pair (2p, 2p+1) = (U, G) for one 16-col H block
  const float is2 = 0.70710678118654752f;
  int cb = ((n0 + wc) >> 1);
#pragma unroll
  for (int i = 0; i < 8; ++i) {
    int row = base + wr + i * 16 + l4 * 4;
#pragma unroll
    for (int p = 0; p < 2; ++p) {
      int col = cb + p * 16 + l15;
#pragma unroll
      for (int r = 0; r < 4; ++r) {
        float u = acc[i][2 * p][r], g = acc[i][2 * p + 1][r];
        float gl = 0.5f * g * (1.0f + erff(g * is2));
        H[(size_t)(row + r) * I_DIM + col] = f2bf(u * gl);
      }
    }
  }
}

// -------- 4) GEMM2 (R6 exact): 256x256, 2-phase dbuf, counted vmcnt ----------
__global__ __launch_bounds__(512, 2) void gemm2_kernel(
    const unsigned short* __restrict__ H, const unsigned short* __restrict__ Dt,
    const unsigned short* __restrict__ sDt, unsigned short* __restrict__ Y,
    const int* __restrict__ meta) {
  int orig = blockIdx.x;
  int wg = (orig & 7) * (GRID_G / 8) + (orig >> 3);
  int mt = wg >> 2, nt = wg & 3;
  int2 m2 = ((const int2*)meta)[mt];
  int e = m2.x;
  if (e < 0) return;
  int base = m2.y;
  int n0 = nt * 256;
  const unsigned short* B = (e < E_EXP) ? Dt + (size_t)e * D_DIM * I_DIM : sDt;

  __shared__ unsigned short As[2 * 256 * 64];
  __shared__ unsigned short Bs[2 * 256 * 64];

  int tid = threadIdx.x, lane = tid & 63, wv = tid >> 6;
  const unsigned short *gA[4], *gB[4];
  int dL[4];
#pragma unroll
  for (int j = 0; j < 4; ++j) {
    int c = j * 512 + tid;
    int row = c >> 3, q = c & 7, qs = q ^ (row & 7);
    gA[j] = H + (size_t)(base + row) * I_DIM + qs * 8;
    gB[j] = B + (size_t)(n0 + row) * I_DIM + qs * 8;
    dL[j] = (j * 512 + wv * 64) * 8;
  }

  f32x4 acc[8][4] = {};
  int wr = (wv >> 2) * 128, wc = (wv & 3) * 64;
  int l15 = lane & 15, l4 = lane >> 4;
  int sx = l15 & 7;

#define STAGE2(buf, k0) do { \
  _Pragma("unroll") \
  for (int j = 0; j < 4; ++j) { \
    gload_lds16(gA[j] + (k0), As + (buf) * 16384 + dL[j]); \
    gload_lds16(gB[j] + (k0), Bs + (buf) * 16384 + dL[j]); \
  } } while (0)

  STAGE2(0, 0);
  const int NK = I_DIM / 64;                     // 8
  for (int t = 0; t < NK; ++t) {
    int cur = t & 1;
    if (t + 1 < NK) {
      STAGE2(cur ^ 1, (t + 1) * 64);
      asm volatile("s_waitcnt vmcnt(8)" ::: "memory");
    } else {
      asm volatile("s_waitcnt vmcnt(0)" ::: "memory");
    }
    __builtin_amdgcn_s_barrier();
#pragma unroll
    for (int kh = 0; kh < 2; ++kh) {
      int kb = kh * 4 + l4;
      bf16x8 af[8], bfr[4];
#pragma unroll
      for (int i = 0; i < 8; ++i)
        af[i] = *reinterpret_cast<const bf16x8*>(&As[cur * 16384 + (wr + i * 16 + l15) * 64 + ((kb ^ sx)) * 8]);
#pragma unroll
      for (int j = 0; j < 4; ++j)
        bfr[j] = *reinterpret_cast<const bf16x8*>(&Bs[cur * 16384 + (wc + j * 16 + l15) * 64 + ((kb ^ sx)) * 8]);
      __builtin_amdgcn_s_setprio(1);
#pragma unroll
      for (int i = 0; i < 8; ++i)
#pragma unroll
        for (int j = 0; j < 4; ++j)
          acc[i][j] = __builtin_amdgcn_mfma_f32_16x16x32_bf16(af[i], bfr[j], acc[i][j], 0, 0, 0);
      __builtin_amdgcn_s_setprio(0);
    }
    asm volatile("" ::: "memory");
    __builtin_amdgcn_s_barrier();
  }
#undef STAGE2

#pragma unroll
  for (int i = 0; i < 8; ++i) {
    int row = base + wr + i * 16 + l4 * 4;
#pragma unroll
    for (int j = 0; j < 4; ++j) {
      int col = n0 + wc + j * 16 + l15;
#pragma unroll
      for (int r = 0; r < 4; ++r)
        Y[(size_t)(row + r) * D_DIM + col] = f2bf(acc[i][j][r]);
    }
  }
}

// ---------------- 5) combine: out = w0*Y[r0] + w1*Y[r1] + Y[shared] ----------------
__global__ void combine_kernel(const unsigned short* __restrict__ Y, const int* __restrict__ inv,
                               const float* __restrict__ tw, float* __restrict__ out) {
  int g = blockIdx.x * 256 + threadIdx.x;
  int t = g >> 7, d0 = (g & 127) * 8;
  int r0 = inv[2 * t], r1 = inv[2 * t + 1];
  float w0 = tw[2 * t], w1 = tw[2 * t + 1];
  ushort8 y0 = *(const ushort8*)&Y[(size_t)r0 * D_DIM + d0];
  ushort8 y1 = *(const ushort8*)&Y[(size_t)r1 * D_DIM + d0];
  ushort8 ys = *(const ushort8*)&Y[(size_t)(SHARED_BASE + t) * D_DIM + d0];
  float o[8];
#pragma unroll
  for (int j = 0; j < 8; ++j)
    o[j] = w0 * bf2f(y0[j]) + w1 * bf2f(y1[j]) + bf2f(ys[j]);
  float4* op = (float4*)(out + (size_t)t * D_DIM + d0);
  op[0] = make_float4(o[0], o[1], o[2], o[3]);
  op[1] = make_float4(o[4], o[5], o[6], o[7]);
}

// ---------------- launcher ----------------
extern "C" void kernel_launch(void* const* d_in, const int* in_sizes, int n_in,
                              void* d_out, int out_size, void* d_ws, size_t ws_size,
                              hipStream_t stream) {
  const float* x    = (const float*)d_in[0];
  const float* gw   = (const float*)d_in[1];
  const float* upw  = (const float*)d_in[2];
  const float* gpw  = (const float*)d_in[3];
  const float* dww  = (const float*)d_in[4];
  const float* sup  = (const float*)d_in[5];
  const float* sgt  = (const float*)d_in[6];
  const float* sdw  = (const float*)d_in[7];
  float* out = (float*)d_out;

  char* ws = (char*)d_ws;
  unsigned short* xb  = (unsigned short*)(ws + OFF_XB);
  unsigned short* UG  = (unsigned short*)(ws + OFF_UG);
  unsigned short* Dt  = (unsigned short*)(ws + OFF_DT);
  unsigned short* sUG = (unsigned short*)(ws + OFF_SUG);
  unsigned short* sDt = (unsigned short*)(ws + OFF_SDT);
  unsigned short* H   = (unsigned short*)(ws + OFF_H);
  unsigned short* Y   = (unsigned short*)(ws + OFF_Y);
  int*   tki   = (int*)(ws + OFF_TOPKI);
  float* tkw   = (float*)(ws + OFF_TOPKW);
  int*   inv   = (int*)(ws + OFF_INV);
  int*   perm  = (int*)(ws + OFF_PERM);
  int*   meta  = (int*)(ws + OFF_META);

  prep_kernel<<<NTRB + T_TOK / 4, 256, 0, stream>>>(x, gw, upw, gpw, dww, sup, sgt, sdw,
                                                    UG, sUG, Dt, sDt, xb, tki, tkw);
  route_kernel<<<1, 1024, 0, stream>>>(tki, meta, perm, inv);

  gemm1_kernel<<<GRID_G, 512, 0, stream>>>(xb, UG, sUG, H, meta, perm);
  gemm2_kernel<<<GRID_G, 512, 0, stream>>>(H, Dt, sDt, Y, meta);
  combine_kernel<<<(T_TOK * 128) / 256, 256, 0, stream>>>(Y, inv, tkw, out);
}